// Round 7
// baseline (341.156 us; speedup 1.0000x reference)
//
#include <hip/hip_runtime.h>

#define NF 64
#define BURST 14
#define NPIX 16384
#define CN (NF * NPIX)
#define LP 72

typedef short bf16x8 __attribute__((ext_vector_type(8)));
typedef float f32x4 __attribute__((ext_vector_type(4)));
typedef unsigned short us4 __attribute__((ext_vector_type(4)));

__device__ inline unsigned short f2bf(float f) {
    unsigned int u = __float_as_uint(f);
    return (unsigned short)((u + 0x7fffu + ((u >> 16) & 1u)) >> 16);
}
__device__ inline float bf2f(unsigned short u) {
    return __uint_as_float(((unsigned int)u) << 16);
}

// ---------------------------------------------------------------------------
// x fp32 [b][c][pix] -> xb bf16 same layout + xT bf16 [b][pix][c] + half sums
// grid (128, 14), block 256
// ---------------------------------------------------------------------------
__global__ __launch_bounds__(256) void cast_x(const float* __restrict__ X,
                                              unsigned short* __restrict__ XB,
                                              unsigned short* __restrict__ XT,
                                              float* __restrict__ S)
{
    __shared__ unsigned short Xs[128][LP];
    __shared__ float red[256];
    const int tid = threadIdx.x;
    const int p0 = blockIdx.x * 128;
    const int b = blockIdx.y;
    const size_t boff = (size_t)b * CN;
#pragma unroll
    for (int i = 0; i < 8; ++i) {
        const int id = tid + 256 * i;
        const int c = id >> 5, p4 = (id & 31) * 4;
        float4 v = *(const float4*)&X[boff + (size_t)c * NPIX + p0 + p4];
        us4 r;
        r.x = f2bf(v.x); r.y = f2bf(v.y); r.z = f2bf(v.z); r.w = f2bf(v.w);
        *(us4*)&XB[boff + (size_t)c * NPIX + p0 + p4] = r;
        Xs[p4 + 0][c] = r.x; Xs[p4 + 1][c] = r.y;
        Xs[p4 + 2][c] = r.z; Xs[p4 + 3][c] = r.w;
    }
    __syncthreads();
#pragma unroll
    for (int i = 0; i < 4; ++i) {
        const int id = tid + 256 * i;
        const int row = id >> 3, c8 = (id & 7) * 8;
        *(bf16x8*)&XT[boff + (size_t)(p0 + row) * 64 + c8] = *(const bf16x8*)&Xs[row][c8];
    }
    {
        const int c = tid & 63, qq = tid >> 6;
        float sv = 0.f;
        for (int pp = qq * 32; pp < qq * 32 + 32; ++pp) sv += bf2f(Xs[pp][c]);
        red[tid] = sv;
        __syncthreads();
        if (tid < 64) {
            const float t = red[tid] + red[64 + tid] + red[128 + tid] + red[192 + tid];
            atomicAdd(&S[(b * 2 + (p0 >= 8192 ? 1 : 0)) * 64 + tid], t);
        }
    }
}

// ---------------------------------------------------------------------------
// Precompute (unchanged from round 5)
// ---------------------------------------------------------------------------
__global__ __launch_bounds__(256) void precompute(
    const float* __restrict__ fus_w, const float* __restrict__ fus_b,
    const float* __restrict__ Wc, const float* __restrict__ bWc,
    const float* __restrict__ Wh, const float* __restrict__ bWh,
    const float* __restrict__ Ww, const float* __restrict__ bWw,
    const float* __restrict__ gcw, const float* __restrict__ ghw,
    const float* __restrict__ gww,
    unsigned short* __restrict__ M16, unsigned short* __restrict__ Wc16,
    float* __restrict__ cb, unsigned short* __restrict__ gT16)
{
    const int blk = blockIdx.x, tid = threadIdx.x;
    if (blk < 42) {
        __shared__ float Fl[64][65];
        __shared__ float Wl[64][65];
        const int g = blk / 14, b = blk % 14;
        const float* Wg = (g == 0) ? Wc : (g == 1) ? Wh : Ww;
#pragma unroll
        for (int i = 0; i < 4; ++i) {
            const int id = tid + 256 * i;
            const int r = id >> 4, c4 = (id & 15) * 4;
            float4 v = *(const float4*)&fus_w[r * 2688 + g * 896 + b * 64 + c4];
            Fl[r][c4] = v.x; Fl[r][c4 + 1] = v.y; Fl[r][c4 + 2] = v.z; Fl[r][c4 + 3] = v.w;
            float4 u = *(const float4*)&Wg[r * 64 + c4];
            Wl[r][c4] = u.x; Wl[r][c4 + 1] = u.y; Wl[r][c4 + 2] = u.z; Wl[r][c4 + 3] = u.w;
        }
        __syncthreads();
        const int o = tid & 63, qq = tid >> 6;
        float s[16];
#pragma unroll
        for (int i = 0; i < 16; ++i) s[i] = 0.f;
        for (int c2 = 0; c2 < 64; ++c2) {
            const float fv = Fl[o][c2];
#pragma unroll
            for (int i = 0; i < 16; ++i) s[i] += fv * Wl[c2][qq * 16 + i];
        }
        unsigned short* Mout = M16 + (size_t)blk * 4096;
#pragma unroll
        for (int i = 0; i < 16; i += 4) {
            us4 r4; r4.x = f2bf(s[i]); r4.y = f2bf(s[i + 1]); r4.z = f2bf(s[i + 2]); r4.w = f2bf(s[i + 3]);
            *(us4*)&Mout[o * 64 + qq * 16 + i] = r4;
        }
    } else if (blk < 98) {
        const int e0 = (blk - 42) * 1024 + tid * 4;
        const int o = e0 / 896, bc = e0 - o * 896;
        float4 a = *(const float4*)&fus_w[o * 2688 + bc];
        float4 b2 = *(const float4*)&fus_w[o * 2688 + 896 + bc];
        float4 c3 = *(const float4*)&fus_w[o * 2688 + 1792 + bc];
        us4 r;
        r.x = f2bf(a.x + b2.x + c3.x); r.y = f2bf(a.y + b2.y + c3.y);
        r.z = f2bf(a.z + b2.z + c3.z); r.w = f2bf(a.w + b2.w + c3.w);
        *(us4*)&Wc16[e0] = r;
    } else if (blk < 106) {
        __shared__ float red[256];
        const int o = (blk - 98) * 8 + (tid >> 5);
        const int lane = tid & 31;
        float s = 0.f;
        for (int t = 0; t < 84; ++t) {
            const int ch = lane + 32 * t;
            const int g = ch / 896, c2 = ch & 63;
            const float bg = (g == 0) ? bWc[c2] : (g == 1) ? bWh[c2] : bWw[c2];
            s += fus_w[o * 2688 + ch] * bg;
        }
        red[tid] = s;
        __syncthreads();
        if (tid < 8) {
            const int oo = (blk - 98) * 8 + tid;
            float t = fus_b[oo];
            for (int i = 0; i < 32; ++i) t += red[tid * 32 + i];
            cb[oo] = t;
        }
    } else {
        const int g = blk - 106;
        const float* wg = (g == 0) ? gcw : (g == 1) ? ghw : gww;
        unsigned short* dst = gT16 + (size_t)g * 4096;
        for (int e = tid; e < 4096; e += 256) {
            const int cp = e >> 6, d = e & 63;
            dst[e] = f2bf(wg[d * 64 + cp]);
        }
    }
}

// ---------------------------------------------------------------------------
// Merged Gram (round-5, proven): grid (32, 14), block 256
// ---------------------------------------------------------------------------
__global__ __launch_bounds__(256) void gram(
    const unsigned short* __restrict__ XB, float* __restrict__ Gpart)
{
    const int tid = threadIdx.x;
    const int w = tid >> 6, l = tid & 63, lm = l & 15, q = l >> 4;
    const int b = blockIdx.y;
    const int mo = (w & 1) * 32, no = (w >> 1) * 32;
    const unsigned short* P = XB;
    const unsigned short* Q = XB + (size_t)b * CN;
    f32x4 a0[2][2] = {}, a1[2][2] = {}, a2[2][2] = {}, a3[2][2] = {}, a4[2][2] = {};
#pragma unroll 2
    for (int ki = 0; ki < 8; ++ki) {
        const int k = blockIdx.x * 256 + ki * 32 + q * 8;
        bf16x8 p0[2], p1[2], qm0[2], qm1[2], qn0[2], qn1[2];
#pragma unroll
        for (int mi = 0; mi < 2; ++mi) {
            const size_t rm = (size_t)(mo + mi * 16 + lm) * NPIX;
            const size_t rn = (size_t)(no + mi * 16 + lm) * NPIX;
            p0[mi]  = *(const bf16x8*)&P[rm + k];
            p1[mi]  = *(const bf16x8*)&P[rm + 8192 + k];
            qm0[mi] = *(const bf16x8*)&Q[rm + k];
            qm1[mi] = *(const bf16x8*)&Q[rm + 8192 + k];
            qn0[mi] = *(const bf16x8*)&Q[rn + k];
            qn1[mi] = *(const bf16x8*)&Q[rn + 8192 + k];
        }
#pragma unroll
        for (int mi = 0; mi < 2; ++mi)
#pragma unroll
            for (int ni = 0; ni < 2; ++ni) {
                a0[mi][ni] = __builtin_amdgcn_mfma_f32_16x16x32_bf16(qm0[mi], qn0[ni], a0[mi][ni], 0, 0, 0);
                a0[mi][ni] = __builtin_amdgcn_mfma_f32_16x16x32_bf16(qm1[mi], qn1[ni], a0[mi][ni], 0, 0, 0);
                a1[mi][ni] = __builtin_amdgcn_mfma_f32_16x16x32_bf16(p0[mi], qn0[ni], a1[mi][ni], 0, 0, 0);
                a2[mi][ni] = __builtin_amdgcn_mfma_f32_16x16x32_bf16(p0[mi], qn1[ni], a2[mi][ni], 0, 0, 0);
                a3[mi][ni] = __builtin_amdgcn_mfma_f32_16x16x32_bf16(p1[mi], qn0[ni], a3[mi][ni], 0, 0, 0);
                a4[mi][ni] = __builtin_amdgcn_mfma_f32_16x16x32_bf16(p1[mi], qn1[ni], a4[mi][ni], 0, 0, 0);
            }
    }
    float* Gp = Gpart + (size_t)(blockIdx.x * 14 + b) * 5 * 4096;
#define STORE_Z(zidx, ACC)                                                     \
    for (int mi = 0; mi < 2; ++mi)                                             \
        for (int r = 0; r < 4; ++r)                                            \
            for (int ni = 0; ni < 2; ++ni)                                     \
                Gp[zidx * 4096 + (mo + mi * 16 + q * 4 + r) * 64 + no + ni * 16 + lm] = ACC[mi][ni][r];
    STORE_Z(0, a0) STORE_Z(1, a1) STORE_Z(2, a2) STORE_Z(3, a3) STORE_Z(4, a4)
#undef STORE_Z
}

__global__ __launch_bounds__(256) void gram_reduce(
    const float* __restrict__ Gpart, float* __restrict__ G)
{
    const int e = blockIdx.x * 256 + threadIdx.x;
    float s = 0.f;
#pragma unroll
    for (int ks = 0; ks < 32; ++ks) s += Gpart[(size_t)ks * 286720 + e];
    G[e] = s;
}

// ---------------------------------------------------------------------------
// Sandwich (unchanged).  grid (14, 9), block 256
// ---------------------------------------------------------------------------
__global__ __launch_bounds__(256) void sandwich(
    const float* __restrict__ thc_w, const float* __restrict__ phc_w,
    const float* __restrict__ thc_b, const float* __restrict__ phc_b,
    const float* __restrict__ thh_w, const float* __restrict__ phh_w,
    const float* __restrict__ thh_b, const float* __restrict__ phh_b,
    const float* __restrict__ thw_w, const float* __restrict__ phw_w,
    const float* __restrict__ thw_b, const float* __restrict__ phw_b,
    const float* __restrict__ G, const float* __restrict__ S,
    float* __restrict__ f1, float* __restrict__ f2)
{
    __shared__ float Wt[64][65], Wp[64][65], Gl[64][65], Tl[64][65];
    __shared__ float sth[64], sph[64], uu[64], vv[64], btl[64], bpl[64];
    const int b = blockIdx.x, y = blockIdx.y, tid = threadIdx.x;
    const float *Wth_g, *Wph_g, *bth_g, *bph_g, *Gp;
    float* outp; int dl = 0, dp = 0; float Kn;
    if (y == 0) {
        Wth_g = thc_w; Wph_g = phc_w; bth_g = thc_b; bph_g = phc_b;
        Gp = G + (size_t)(b * 5) * 4096; Kn = 16384.f;
        outp = f1 + (size_t)b * 4096;
    } else {
        const int part = (y - 1) / 4, e = (y - 1) & 3;
        dl = e >> 1; dp = e & 1;
        if (part == 0) { Wth_g = thh_w; Wph_g = phh_w; bth_g = thh_b; bph_g = phh_b; }
        else           { Wth_g = thw_w; Wph_g = phw_w; bth_g = thw_b; bph_g = phw_b; }
        Gp = G + (size_t)(b * 5 + 1 + e) * 4096; Kn = 8192.f;
        outp = f2 + (size_t)(part * 14 + b) * 16384;
    }
#pragma unroll
    for (int i = 0; i < 4; ++i) {
        const int id = tid + 256 * i;
        const int r = id >> 4, c4 = (id & 15) * 4;
        float4 v = *(const float4*)&Wth_g[r * 64 + c4];
        Wt[r][c4] = v.x; Wt[r][c4 + 1] = v.y; Wt[r][c4 + 2] = v.z; Wt[r][c4 + 3] = v.w;
        float4 u = *(const float4*)&Wph_g[r * 64 + c4];
        Wp[r][c4] = u.x; Wp[r][c4 + 1] = u.y; Wp[r][c4 + 2] = u.z; Wp[r][c4 + 3] = u.w;
        float4 g = *(const float4*)&Gp[r * 64 + c4];
        Gl[r][c4] = g.x; Gl[r][c4 + 1] = g.y; Gl[r][c4 + 2] = g.z; Gl[r][c4 + 3] = g.w;
    }
    if (tid < 64) {
        if (y == 0) { const float sf = S[b * 128 + tid] + S[b * 128 + 64 + tid]; sth[tid] = sf; sph[tid] = sf; }
        else { sth[tid] = S[dl * 64 + tid]; sph[tid] = S[b * 128 + dp * 64 + tid]; }
        btl[tid] = bth_g[tid]; bpl[tid] = bph_g[tid];
    }
    __syncthreads();
    if (tid < 64) {
        float su = 0.f, sv = 0.f;
        for (int c = 0; c < 64; ++c) { su += Wt[tid][c] * sth[c]; sv += Wp[tid][c] * sph[c]; }
        uu[tid] = su; vv[tid] = sv;
    }
    const int t = tid & 63, qq = tid >> 6;
    float r16[16];
#pragma unroll
    for (int i = 0; i < 16; ++i) r16[i] = 0.f;
    for (int c = 0; c < 64; ++c) {
        const float fv = Wt[t][c];
#pragma unroll
        for (int i = 0; i < 16; ++i) r16[i] += fv * Gl[c][qq * 16 + i];
    }
#pragma unroll
    for (int i = 0; i < 16; ++i) Tl[t][qq * 16 + i] = r16[i];
    __syncthreads();
#pragma unroll
    for (int i = 0; i < 16; ++i) r16[i] = 0.f;
    for (int c = 0; c < 64; ++c) {
        const float tv = Tl[t][c];
#pragma unroll
        for (int i = 0; i < 16; ++i) r16[i] += tv * Wp[qq * 16 + i][c];
    }
    if (y == 0) {
#pragma unroll
        for (int i = 0; i < 16; ++i) {
            const int d = qq * 16 + i;
            outp[t * 64 + d] = r16[i] + uu[t] * bpl[d] + btl[t] * vv[d] + Kn * btl[t] * bpl[d];
        }
    } else {
#pragma unroll
        for (int i = 0; i < 16; ++i) {
            const int tp = qq * 16 + i;
            outp[(2 * t + dl) * 128 + 2 * tp + dp] =
                r16[i] + uu[t] * bpl[tp] + btl[t] * vv[tp] + Kn * btl[t] * bpl[tp];
        }
    }
}

// ---------------------------------------------------------------------------
// Merged softmax + bias dots + de-interleave (unchanged)
// ---------------------------------------------------------------------------
__global__ __launch_bounds__(256) void softmax_all(
    const float* __restrict__ f1, const float* __restrict__ f2,
    const float* __restrict__ gcb, const float* __restrict__ ghb,
    const float* __restrict__ gwb,
    unsigned short* __restrict__ o1, unsigned short* __restrict__ o2d,
    float* __restrict__ B1, float* __restrict__ B2)
{
    __shared__ float red[256];
    __shared__ float mxA[128], invA[128];
    __shared__ float bgl[64];
    const int bx = blockIdx.x, tid = threadIdx.x;
    if (bx < 14) {
        const float* Fb = f1 + (size_t)bx * 4096;
        unsigned short* Ob = o1 + (size_t)bx * 4096;
        if (tid < 64) bgl[tid] = gcb[tid];
        const int d = tid & 63, qq = tid >> 6;
        float mx = -1e30f;
        for (int c = qq * 16; c < qq * 16 + 16; ++c) mx = fmaxf(mx, Fb[c * 64 + d]);
        red[tid] = mx;
        __syncthreads();
        if (tid < 64) mxA[tid] = fmaxf(fmaxf(red[tid], red[64 + tid]), fmaxf(red[128 + tid], red[192 + tid]));
        __syncthreads();
        const float m = mxA[d];
        float s = 0.f;
        for (int c = qq * 16; c < qq * 16 + 16; ++c) s += __expf(Fb[c * 64 + d] - m);
        red[tid] = s;
        __syncthreads();
        if (tid < 64) invA[tid] = 1.f / (red[tid] + red[64 + tid] + red[128 + tid] + red[192 + tid]);
        __syncthreads();
        const int e0 = tid * 16;
        const int d0 = e0 & 63;
        float bp = 0.f;
#pragma unroll
        for (int i = 0; i < 16; i += 4) {
            us4 r4;
            float v0 = __expf(Fb[e0 + i] - mxA[d0 + i]) * invA[d0 + i];
            float v1 = __expf(Fb[e0 + i + 1] - mxA[d0 + i + 1]) * invA[d0 + i + 1];
            float v2 = __expf(Fb[e0 + i + 2] - mxA[d0 + i + 2]) * invA[d0 + i + 2];
            float v3 = __expf(Fb[e0 + i + 3] - mxA[d0 + i + 3]) * invA[d0 + i + 3];
            bp += v0 * bgl[d0 + i] + v1 * bgl[d0 + i + 1] + v2 * bgl[d0 + i + 2] + v3 * bgl[d0 + i + 3];
            r4.x = f2bf(v0); r4.y = f2bf(v1); r4.z = f2bf(v2); r4.w = f2bf(v3);
            *(us4*)&Ob[e0 + i] = r4;
        }
        red[tid] = bp;
        __syncthreads();
        if (tid < 64)
            B1[bx * 64 + tid] = red[tid * 4] + red[tid * 4 + 1] + red[tid * 4 + 2] + red[tid * 4 + 3];
    } else {
        const int idx = bx - 14;
        const float* Fb = f2 + (size_t)idx * 16384;
        if (tid < 64) bgl[tid] = (idx < 14) ? ghb[tid] : gwb[tid];
        const int j = tid & 127, ih = tid >> 7;
        float mx = -1e30f;
        for (int i = ih * 64; i < ih * 64 + 64; ++i) mx = fmaxf(mx, Fb[i * 128 + j]);
        red[tid] = mx;
        __syncthreads();
        if (tid < 128) mxA[tid] = fmaxf(red[tid], red[128 + tid]);
        __syncthreads();
        const float m = mxA[j];
        float s = 0.f;
        for (int i = ih * 64; i < ih * 64 + 64; ++i) s += __expf(Fb[i * 128 + j] - m);
        red[tid] = s;
        __syncthreads();
        if (tid < 128) invA[tid] = 1.f / (red[tid] + red[128 + tid]);
        __syncthreads();
        const int e0 = tid * 64;
        const int irow = tid >> 1;
        const int j0 = e0 & 127;
        unsigned short vt[2][32];
        float bp = 0.f;
        for (int ii = 0; ii < 64; ++ii) {
            const int jj = j0 + ii;
            const float v = __expf(Fb[e0 + ii] - mxA[jj]) * invA[jj];
            bp += v * bgl[jj >> 1];
            vt[jj & 1][ii >> 1] = f2bf(v);
        }
        unsigned short* Od = o2d + (size_t)idx * 16384 + irow * 64 + (j0 >> 1);
#pragma unroll
        for (int dlt = 0; dlt < 2; ++dlt)
#pragma unroll
            for (int ss = 0; ss < 32; ss += 4)
                *(us4*)&Od[dlt * 8192 + ss] = *(us4*)&vt[dlt][ss];
        red[tid] = bp;
        __syncthreads();
        if (tid < 128) B2[idx * 128 + tid] = red[2 * tid] + red[2 * tid + 1];
    }
}

// ---------------------------------------------------------------------------
// kmat via MFMA (unchanged).  grid (14, 3), block 256
// ---------------------------------------------------------------------------
__global__ __launch_bounds__(256) void kmat(
    const unsigned short* __restrict__ f16_1, const unsigned short* __restrict__ f2d,
    const unsigned short* __restrict__ gT16,
    unsigned short* __restrict__ K1, unsigned short* __restrict__ K2)
{
    const int b = blockIdx.x, y = blockIdx.y, tid = threadIdx.x;
    const int w = tid >> 6, l = tid & 63, lm = l & 15, q = l >> 4;
    if (y == 0) {
        const unsigned short* A = f16_1 + (size_t)b * 4096;
        const unsigned short* Bm = gT16;
        const int mo = (w & 1) * 32, no = (w >> 1) * 32;
        f32x4 acc[2][2] = {};
#pragma unroll
        for (int ks = 0; ks < 2; ++ks) {
            const int k = ks * 32 + q * 8;
            bf16x8 a[2], bb[2];
#pragma unroll
            for (int mi = 0; mi < 2; ++mi) a[mi] = *(const bf16x8*)&A[(mo + mi * 16 + lm) * 64 + k];
#pragma unroll
            for (int ni = 0; ni < 2; ++ni) bb[ni] = *(const bf16x8*)&Bm[(no + ni * 16 + lm) * 64 + k];
#pragma unroll
            for (int mi = 0; mi < 2; ++mi)
#pragma unroll
                for (int ni = 0; ni < 2; ++ni)
                    acc[mi][ni] = __builtin_amdgcn_mfma_f32_16x16x32_bf16(a[mi], bb[ni], acc[mi][ni], 0, 0, 0);
        }
        unsigned short* Kp = K1 + (size_t)b * 4096;
#pragma unroll
        for (int mi = 0; mi < 2; ++mi)
#pragma unroll
            for (int r = 0; r < 4; ++r)
#pragma unroll
                for (int ni = 0; ni < 2; ++ni)
                    Kp[(mo + mi * 16 + q * 4 + r) * 64 + no + ni * 16 + lm] = f2bf(acc[mi][ni][r]);
    } else {
        const int part = y - 1;
        const unsigned short* Bm = gT16 + (size_t)(1 + part) * 4096;
        unsigned short* Kp = K2 + (size_t)(part * 14 + b) * 16384;
        for (int dlt = 0; dlt < 2; ++dlt) {
            const unsigned short* A = f2d + (size_t)(part * 14 + b) * 16384 + dlt * 8192;
            const int mo = (w & 1) * 64, no = (w >> 1) * 32;
            f32x4 acc[4][2] = {};
#pragma unroll
            for (int ks = 0; ks < 2; ++ks) {
                const int k = ks * 32 + q * 8;
                bf16x8 a[4], bb[2];
#pragma unroll
                for (int mi = 0; mi < 4; ++mi) a[mi] = *(const bf16x8*)&A[(mo + mi * 16 + lm) * 64 + k];
#pragma unroll
                for (int ni = 0; ni < 2; ++ni) bb[ni] = *(const bf16x8*)&Bm[(no + ni * 16 + lm) * 64 + k];
#pragma unroll
                for (int mi = 0; mi < 4; ++mi)
#pragma unroll
                    for (int ni = 0; ni < 2; ++ni)
                        acc[mi][ni] = __builtin_amdgcn_mfma_f32_16x16x32_bf16(a[mi], bb[ni], acc[mi][ni], 0, 0, 0);
            }
#pragma unroll
            for (int mi = 0; mi < 4; ++mi)
#pragma unroll
                for (int r = 0; r < 4; ++r)
#pragma unroll
                    for (int ni = 0; ni < 2; ++ni)
                        Kp[dlt * 8192 + (mo + mi * 16 + q * 4 + r) * 64 + no + ni * 16 + lm] = f2bf(acc[mi][ni][r]);
        }
    }
}

// ---------------------------------------------------------------------------
// Fused PV + fold + residual: one block computes out tile [64 o][64 pix]
// for b in [bh*7, bh*7+7), via stage1 (xT x K -> y-tile, bf16, LDS) and
// stage2 (M x y-tile -> acc), double-buffered.  atomicAdd into out.
// grid (256, 2), block 256.
// ---------------------------------------------------------------------------
__device__ __forceinline__ void s1_p1(
    const unsigned short* __restrict__ XT, const unsigned short* __restrict__ K1,
    const float* __restrict__ B1, int b, int h1,
    int mo, int no, int lm, int q, unsigned short (*Yb)[LP])
{
    f32x4 acc[2][2] = {};
    const unsigned short* Xb = XT + (size_t)b * CN;
    const unsigned short* Kb = K1 + (size_t)b * 4096;
#pragma unroll
    for (int ks = 0; ks < 2; ++ks) {
        const int c0 = ks * 32 + q * 8;
        bf16x8 a[2], bb[2];
#pragma unroll
        for (int mi = 0; mi < 2; ++mi)
            a[mi] = *(const bf16x8*)&Xb[((size_t)(mo + mi * 16 + lm) * 256 + h1) * 64 + c0];
#pragma unroll
        for (int ni = 0; ni < 2; ++ni)
            bb[ni] = *(const bf16x8*)&Kb[(no + ni * 16 + lm) * 64 + c0];
#pragma unroll
        for (int mi = 0; mi < 2; ++mi)
#pragma unroll
            for (int ni = 0; ni < 2; ++ni)
                acc[mi][ni] = __builtin_amdgcn_mfma_f32_16x16x32_bf16(a[mi], bb[ni], acc[mi][ni], 0, 0, 0);
    }
#pragma unroll
    for (int mi = 0; mi < 2; ++mi)
#pragma unroll
        for (int r = 0; r < 4; ++r) {
            const int c2 = mo + mi * 16 + q * 4 + r;
#pragma unroll
            for (int ni = 0; ni < 2; ++ni) {
                const int c = no + ni * 16 + lm;
                Yb[c][c2] = f2bf(acc[mi][ni][r] + B1[b * 64 + c]);
            }
        }
}

__device__ __forceinline__ void s1_p23(
    const unsigned short* __restrict__ XT, const unsigned short* __restrict__ K2,
    const float* __restrict__ B2, int part, int b, int h2, int i0,
    int mo, int no, int lm, int q, unsigned short (*Yb)[LP])
{
    f32x4 acc[2][2] = {};
    const unsigned short* Xb = XT + (size_t)b * CN;
    const unsigned short* Kb = K2 + (size_t)(part * 14 + b) * 16384;
    const float* Bb = B2 + (part * 14 + b) * 128;
#pragma unroll
    for (int dlt = 0; dlt < 2; ++dlt)
#pragma unroll
        for (int ks = 0; ks < 2; ++ks) {
            const int c0 = ks * 32 + q * 8;
            bf16x8 a[2], bb[2];
#pragma unroll
            for (int mi = 0; mi < 2; ++mi)
                a[mi] = *(const bf16x8*)&Xb[((size_t)dlt * 8192 + (size_t)(mo + mi * 16 + lm) * 128 + h2) * 64 + c0];
#pragma unroll
            for (int ni = 0; ni < 2; ++ni)
                bb[ni] = *(const bf16x8*)&Kb[dlt * 8192 + (i0 + no + ni * 16 + lm) * 64 + c0];
#pragma unroll
            for (int mi = 0; mi < 2; ++mi)
#pragma unroll
                for (int ni = 0; ni < 2; ++ni)
                    acc[mi][ni] = __builtin_amdgcn_mfma_f32_16x16x32_bf16(a[mi], bb[ni], acc[mi][ni], 0, 0, 0);
        }
#pragma unroll
    for (int mi = 0; mi < 2; ++mi)
#pragma unroll
        for (int r = 0; r < 4; ++r) {
            const int c2 = mo + mi * 16 + q * 4 + r;
#pragma unroll
            for (int ni = 0; ni < 2; ++ni) {
                const int iiL = no + ni * 16 + lm;
                Yb[iiL][c2] = f2bf(acc[mi][ni][r] + Bb[i0 + iiL]);
            }
        }
}

__device__ __forceinline__ void s2(
    const unsigned short* __restrict__ M16, int z, int b,
    int mo, int no, int lm, int q, const unsigned short (*Yb)[LP],
    f32x4 (*oacc)[2])
{
    const unsigned short* Mp = M16 + (size_t)(z * 14 + b) * 4096;
#pragma unroll
    for (int ks = 0; ks < 2; ++ks) {
        const int c0 = ks * 32 + q * 8;
        bf16x8 a[2], bb[2];
#pragma unroll
        for (int mi = 0; mi < 2; ++mi)
            a[mi] = *(const bf16x8*)&Mp[(mo + mi * 16 + lm) * 64 + c0];
#pragma unroll
        for (int ni = 0; ni < 2; ++ni)
            bb[ni] = *(const bf16x8*)&Yb[no + ni * 16 + lm][c0];
#pragma unroll
        for (int mi = 0; mi < 2; ++mi)
#pragma unroll
            for (int ni = 0; ni < 2; ++ni)
                oacc[mi][ni] = __builtin_amdgcn_mfma_f32_16x16x32_bf16(a[mi], bb[ni], oacc[mi][ni], 0, 0, 0);
    }
}

__global__ __launch_bounds__(256) void pvfold(
    const unsigned short* __restrict__ XT,
    const unsigned short* __restrict__ K1, const float* __restrict__ B1,
    const unsigned short* __restrict__ K2, const float* __restrict__ B2,
    const unsigned short* __restrict__ M16,
    const unsigned short* __restrict__ Wcomb,
    float* __restrict__ Out)
{
    __shared__ unsigned short Ys[2][64][LP];
    const int tid = threadIdx.x;
    const int w = tid >> 6, l = tid & 63, lm = l & 15, q = l >> 4;
    const int P0 = blockIdx.x * 64;
    const int h1 = blockIdx.x;
    const int h2 = blockIdx.x >> 1;
    const int i0 = (blockIdx.x & 1) * 64;
    const int b0 = blockIdx.y * 7;
    const int mo = (w & 1) * 32, no = (w >> 1) * 32;
    f32x4 oacc[2][2] = {};

    // residual: out += Wcomb[:, b*64:] @ xT[b][P0..P0+64][:]
    for (int b = b0; b < b0 + 7; ++b) {
#pragma unroll
        for (int ks = 0; ks < 2; ++ks) {
            const int c0 = ks * 32 + q * 8;
            bf16x8 a[2], bb[2];
#pragma unroll
            for (int mi = 0; mi < 2; ++mi)
                a[mi] = *(const bf16x8*)&Wcomb[(mo + mi * 16 + lm) * 896 + b * 64 + c0];
#pragma unroll
            for (int ni = 0; ni < 2; ++ni)
                bb[ni] = *(const bf16x8*)&XT[(size_t)b * CN + (size_t)(P0 + no + ni * 16 + lm) * 64 + c0];
#pragma unroll
            for (int mi = 0; mi < 2; ++mi)
#pragma unroll
                for (int ni = 0; ni < 2; ++ni)
                    oacc[mi][ni] = __builtin_amdgcn_mfma_f32_16x16x32_bf16(a[mi], bb[ni], oacc[mi][ni], 0, 0, 0);
        }
    }

    // pipelined PV: per b: p1 -> z0, p2 -> z1, p3 -> z2
    int cur = 0;
    s1_p1(XT, K1, B1, b0, h1, mo, no, lm, q, Ys[0]);
    for (int b = b0; b < b0 + 7; ++b) {
        __syncthreads();
        s2(M16, 0, b, mo, no, lm, q, (const unsigned short (*)[LP])Ys[cur], oacc);
        s1_p23(XT, K2, B2, 0, b, h2, i0, mo, no, lm, q, Ys[cur ^ 1]);
        __syncthreads();
        s2(M16, 1, b, mo, no, lm, q, (const unsigned short (*)[LP])Ys[cur ^ 1], oacc);
        s1_p23(XT, K2, B2, 1, b, h2, i0, mo, no, lm, q, Ys[cur]);
        __syncthreads();
        s2(M16, 2, b, mo, no, lm, q, (const unsigned short (*)[LP])Ys[cur], oacc);
        if (b + 1 < b0 + 7) s1_p1(XT, K1, B1, b + 1, h1, mo, no, lm, q, Ys[cur ^ 1]);
        cur ^= 1;
    }

#pragma unroll
    for (int mi = 0; mi < 2; ++mi)
#pragma unroll
        for (int r = 0; r < 4; ++r) {
            const int o = mo + mi * 16 + q * 4 + r;
#pragma unroll
            for (int ni = 0; ni < 2; ++ni)
                atomicAdd(&Out[(size_t)o * NPIX + P0 + no + ni * 16 + lm], oacc[mi][ni][r]);
        }
}

// out = leaky(out + cb[o])
__global__ __launch_bounds__(256) void leaky_cb(float* __restrict__ O, const float* __restrict__ cb)
{
    const int i = blockIdx.x * 256 + threadIdx.x;
    float4 v = ((float4*)O)[i];
    const float b = cb[(i * 4) >> 14];
    v.x += b; v.y += b; v.z += b; v.w += b;
    v.x = v.x >= 0.f ? v.x : 0.2f * v.x;
    v.y = v.y >= 0.f ? v.y : 0.2f * v.y;
    v.z = v.z >= 0.f ? v.z : 0.2f * v.z;
    v.w = v.w >= 0.f ? v.w : 0.2f * v.w;
    ((float4*)O)[i] = v;
}

extern "C" void kernel_launch(void* const* d_in, const int* in_sizes, int n_in,
                              void* d_out, int out_size, void* d_ws, size_t ws_size,
                              hipStream_t stream)
{
    const float* x     = (const float*)d_in[0];
    const float* gc_w  = (const float*)d_in[1];
    const float* gc_b  = (const float*)d_in[2];
    const float* thc_w = (const float*)d_in[3];
    const float* thc_b = (const float*)d_in[4];
    const float* phc_w = (const float*)d_in[5];
    const float* phc_b = (const float*)d_in[6];
    const float* Wc_w  = (const float*)d_in[7];
    const float* Wc_b  = (const float*)d_in[8];
    const float* gh_w  = (const float*)d_in[9];
    const float* gh_b  = (const float*)d_in[10];
    const float* thh_w = (const float*)d_in[11];
    const float* thh_b = (const float*)d_in[12];
    const float* phh_w = (const float*)d_in[13];
    const float* phh_b = (const float*)d_in[14];
    const float* Wh_w  = (const float*)d_in[15];
    const float* Wh_b  = (const float*)d_in[16];
    const float* gw_w  = (const float*)d_in[17];
    const float* gw_b  = (const float*)d_in[18];
    const float* thw_w = (const float*)d_in[19];
    const float* thw_b = (const float*)d_in[20];
    const float* phw_w = (const float*)d_in[21];
    const float* phw_b = (const float*)d_in[22];
    const float* Ww_w  = (const float*)d_in[23];
    const float* Ww_b  = (const float*)d_in[24];
    const float* fus_w = (const float*)d_in[25];
    const float* fus_b = (const float*)d_in[26];

    float* out = (float*)d_out;

    char* p = (char*)d_ws;
    unsigned short* xb   = (unsigned short*)p; p += (size_t)BURST * CN * 2;
    unsigned short* xT   = (unsigned short*)p; p += (size_t)BURST * CN * 2;
    float*          Gpart = (float*)p;         p += (size_t)32 * 286720 * 4;
    float*          Gbuf = (float*)p;          p += (size_t)BURST * 5 * 4096 * 4;
    float*          sbuf = (float*)p;          p += (size_t)BURST * 2 * 64 * 4;
    float*          f1b  = (float*)p;          p += (size_t)BURST * 4096 * 4;
    float*          f2b  = (float*)p;          p += (size_t)2 * BURST * 16384 * 4;
    unsigned short* f16_1 = (unsigned short*)p; p += (size_t)BURST * 4096 * 2;
    unsigned short* f2d  = (unsigned short*)p; p += (size_t)2 * BURST * 16384 * 2;
    unsigned short* K1   = (unsigned short*)p; p += (size_t)BURST * 4096 * 2;
    unsigned short* K2   = (unsigned short*)p; p += (size_t)2 * BURST * 16384 * 2;
    float*          B1   = (float*)p;          p += (size_t)BURST * 64 * 4;
    float*          B2   = (float*)p;          p += (size_t)2 * BURST * 128 * 4;
    unsigned short* M16  = (unsigned short*)p; p += (size_t)42 * 4096 * 2;
    unsigned short* Wc16 = (unsigned short*)p; p += (size_t)64 * 896 * 2;
    unsigned short* gT16 = (unsigned short*)p; p += (size_t)3 * 4096 * 2;
    float*          cbv  = (float*)p;          p += 256;

    hipMemsetAsync(sbuf, 0, (size_t)BURST * 2 * 64 * 4, stream);
    hipMemsetAsync(out, 0, (size_t)NF * NPIX * 4, stream);

    cast_x<<<dim3(128, 14), 256, 0, stream>>>(x, xb, xT, sbuf);
    precompute<<<109, 256, 0, stream>>>(fus_w, fus_b, Wc_w, Wc_b, Wh_w, Wh_b, Ww_w, Ww_b,
                                        gc_w, gh_w, gw_w, M16, Wc16, cbv, gT16);
    gram<<<dim3(32, 14), 256, 0, stream>>>(xb, Gpart);
    gram_reduce<<<1120, 256, 0, stream>>>(Gpart, Gbuf);
    sandwich<<<dim3(14, 9), 256, 0, stream>>>(
        thc_w, phc_w, thc_b, phc_b, thh_w, phh_w, thh_b, phh_b,
        thw_w, phw_w, thw_b, phw_b, Gbuf, sbuf, f1b, f2b);
    softmax_all<<<42, 256, 0, stream>>>(f1b, f2b, gc_b, gh_b, gw_b,
                                        f16_1, f2d, B1, B2);
    kmat<<<dim3(14, 3), 256, 0, stream>>>(f16_1, f2d, gT16, K1, K2);
    pvfold<<<dim3(256, 2), 256, 0, stream>>>(xT, K1, B1, K2, B2, M16, Wc16, out);
    leaky_cb<<<1024, 256, 0, stream>>>(out, cbv);
}

// Round 8
// 335.416 us; speedup vs baseline: 1.0171x; 1.0171x over previous
//
#include <hip/hip_runtime.h>

#define NF 64
#define BURST 14
#define NPIX 16384
#define CN (NF * NPIX)
#define LP 72

typedef short bf16x8 __attribute__((ext_vector_type(8)));
typedef float f32x4 __attribute__((ext_vector_type(4)));
typedef unsigned short us4 __attribute__((ext_vector_type(4)));

__device__ inline unsigned short f2bf(float f) {
    unsigned int u = __float_as_uint(f);
    return (unsigned short)((u + 0x7fffu + ((u >> 16) & 1u)) >> 16);
}
__device__ inline float bf2f(unsigned short u) {
    return __uint_as_float(((unsigned int)u) << 16);
}

// ---------------------------------------------------------------------------
// x fp32 [b][c][pix] -> xb bf16 same layout + xT bf16 [b][pix][c] + half sums
// grid (128, 14), block 256
// ---------------------------------------------------------------------------
__global__ __launch_bounds__(256) void cast_x(const float* __restrict__ X,
                                              unsigned short* __restrict__ XB,
                                              unsigned short* __restrict__ XT,
                                              float* __restrict__ S)
{
    __shared__ unsigned short Xs[128][LP];
    __shared__ float red[256];
    const int tid = threadIdx.x;
    const int p0 = blockIdx.x * 128;
    const int b = blockIdx.y;
    const size_t boff = (size_t)b * CN;
#pragma unroll
    for (int i = 0; i < 8; ++i) {
        const int id = tid + 256 * i;
        const int c = id >> 5, p4 = (id & 31) * 4;
        float4 v = *(const float4*)&X[boff + (size_t)c * NPIX + p0 + p4];
        us4 r;
        r.x = f2bf(v.x); r.y = f2bf(v.y); r.z = f2bf(v.z); r.w = f2bf(v.w);
        *(us4*)&XB[boff + (size_t)c * NPIX + p0 + p4] = r;
        Xs[p4 + 0][c] = r.x; Xs[p4 + 1][c] = r.y;
        Xs[p4 + 2][c] = r.z; Xs[p4 + 3][c] = r.w;
    }
    __syncthreads();
#pragma unroll
    for (int i = 0; i < 4; ++i) {
        const int id = tid + 256 * i;
        const int row = id >> 3, c8 = (id & 7) * 8;
        *(bf16x8*)&XT[boff + (size_t)(p0 + row) * 64 + c8] = *(const bf16x8*)&Xs[row][c8];
    }
    {
        const int c = tid & 63, qq = tid >> 6;
        float sv = 0.f;
        for (int pp = qq * 32; pp < qq * 32 + 32; ++pp) sv += bf2f(Xs[pp][c]);
        red[tid] = sv;
        __syncthreads();
        if (tid < 64) {
            const float t = red[tid] + red[64 + tid] + red[128 + tid] + red[192 + tid];
            atomicAdd(&S[(b * 2 + (p0 >= 8192 ? 1 : 0)) * 64 + tid], t);
        }
    }
}

// ---------------------------------------------------------------------------
// Precompute (unchanged)
// ---------------------------------------------------------------------------
__global__ __launch_bounds__(256) void precompute(
    const float* __restrict__ fus_w, const float* __restrict__ fus_b,
    const float* __restrict__ Wc, const float* __restrict__ bWc,
    const float* __restrict__ Wh, const float* __restrict__ bWh,
    const float* __restrict__ Ww, const float* __restrict__ bWw,
    const float* __restrict__ gcw, const float* __restrict__ ghw,
    const float* __restrict__ gww,
    unsigned short* __restrict__ M16, unsigned short* __restrict__ Wc16,
    float* __restrict__ cb, unsigned short* __restrict__ gT16)
{
    const int blk = blockIdx.x, tid = threadIdx.x;
    if (blk < 42) {
        __shared__ float Fl[64][65];
        __shared__ float Wl[64][65];
        const int g = blk / 14, b = blk % 14;
        const float* Wg = (g == 0) ? Wc : (g == 1) ? Wh : Ww;
#pragma unroll
        for (int i = 0; i < 4; ++i) {
            const int id = tid + 256 * i;
            const int r = id >> 4, c4 = (id & 15) * 4;
            float4 v = *(const float4*)&fus_w[r * 2688 + g * 896 + b * 64 + c4];
            Fl[r][c4] = v.x; Fl[r][c4 + 1] = v.y; Fl[r][c4 + 2] = v.z; Fl[r][c4 + 3] = v.w;
            float4 u = *(const float4*)&Wg[r * 64 + c4];
            Wl[r][c4] = u.x; Wl[r][c4 + 1] = u.y; Wl[r][c4 + 2] = u.z; Wl[r][c4 + 3] = u.w;
        }
        __syncthreads();
        const int o = tid & 63, qq = tid >> 6;
        float s[16];
#pragma unroll
        for (int i = 0; i < 16; ++i) s[i] = 0.f;
        for (int c2 = 0; c2 < 64; ++c2) {
            const float fv = Fl[o][c2];
#pragma unroll
            for (int i = 0; i < 16; ++i) s[i] += fv * Wl[c2][qq * 16 + i];
        }
        unsigned short* Mout = M16 + (size_t)blk * 4096;
#pragma unroll
        for (int i = 0; i < 16; i += 4) {
            us4 r4; r4.x = f2bf(s[i]); r4.y = f2bf(s[i + 1]); r4.z = f2bf(s[i + 2]); r4.w = f2bf(s[i + 3]);
            *(us4*)&Mout[o * 64 + qq * 16 + i] = r4;
        }
    } else if (blk < 98) {
        const int e0 = (blk - 42) * 1024 + tid * 4;
        const int o = e0 / 896, bc = e0 - o * 896;
        float4 a = *(const float4*)&fus_w[o * 2688 + bc];
        float4 b2 = *(const float4*)&fus_w[o * 2688 + 896 + bc];
        float4 c3 = *(const float4*)&fus_w[o * 2688 + 1792 + bc];
        us4 r;
        r.x = f2bf(a.x + b2.x + c3.x); r.y = f2bf(a.y + b2.y + c3.y);
        r.z = f2bf(a.z + b2.z + c3.z); r.w = f2bf(a.w + b2.w + c3.w);
        *(us4*)&Wc16[e0] = r;
    } else if (blk < 106) {
        __shared__ float red[256];
        const int o = (blk - 98) * 8 + (tid >> 5);
        const int lane = tid & 31;
        float s = 0.f;
        for (int t = 0; t < 84; ++t) {
            const int ch = lane + 32 * t;
            const int g = ch / 896, c2 = ch & 63;
            const float bg = (g == 0) ? bWc[c2] : (g == 1) ? bWh[c2] : bWw[c2];
            s += fus_w[o * 2688 + ch] * bg;
        }
        red[tid] = s;
        __syncthreads();
        if (tid < 8) {
            const int oo = (blk - 98) * 8 + tid;
            float t = fus_b[oo];
            for (int i = 0; i < 32; ++i) t += red[tid * 32 + i];
            cb[oo] = t;
        }
    } else {
        const int g = blk - 106;
        const float* wg = (g == 0) ? gcw : (g == 1) ? ghw : gww;
        unsigned short* dst = gT16 + (size_t)g * 4096;
        for (int e = tid; e < 4096; e += 256) {
            const int cp = e >> 6, d = e & 63;
            dst[e] = f2bf(wg[d * 64 + cp]);
        }
    }
}

// ---------------------------------------------------------------------------
// Merged Gram (unchanged): grid (32, 14), block 256
// ---------------------------------------------------------------------------
__global__ __launch_bounds__(256) void gram(
    const unsigned short* __restrict__ XB, float* __restrict__ Gpart)
{
    const int tid = threadIdx.x;
    const int w = tid >> 6, l = tid & 63, lm = l & 15, q = l >> 4;
    const int b = blockIdx.y;
    const int mo = (w & 1) * 32, no = (w >> 1) * 32;
    const unsigned short* P = XB;
    const unsigned short* Q = XB + (size_t)b * CN;
    f32x4 a0[2][2] = {}, a1[2][2] = {}, a2[2][2] = {}, a3[2][2] = {}, a4[2][2] = {};
#pragma unroll 2
    for (int ki = 0; ki < 8; ++ki) {
        const int k = blockIdx.x * 256 + ki * 32 + q * 8;
        bf16x8 p0[2], p1[2], qm0[2], qm1[2], qn0[2], qn1[2];
#pragma unroll
        for (int mi = 0; mi < 2; ++mi) {
            const size_t rm = (size_t)(mo + mi * 16 + lm) * NPIX;
            const size_t rn = (size_t)(no + mi * 16 + lm) * NPIX;
            p0[mi]  = *(const bf16x8*)&P[rm + k];
            p1[mi]  = *(const bf16x8*)&P[rm + 8192 + k];
            qm0[mi] = *(const bf16x8*)&Q[rm + k];
            qm1[mi] = *(const bf16x8*)&Q[rm + 8192 + k];
            qn0[mi] = *(const bf16x8*)&Q[rn + k];
            qn1[mi] = *(const bf16x8*)&Q[rn + 8192 + k];
        }
#pragma unroll
        for (int mi = 0; mi < 2; ++mi)
#pragma unroll
            for (int ni = 0; ni < 2; ++ni) {
                a0[mi][ni] = __builtin_amdgcn_mfma_f32_16x16x32_bf16(qm0[mi], qn0[ni], a0[mi][ni], 0, 0, 0);
                a0[mi][ni] = __builtin_amdgcn_mfma_f32_16x16x32_bf16(qm1[mi], qn1[ni], a0[mi][ni], 0, 0, 0);
                a1[mi][ni] = __builtin_amdgcn_mfma_f32_16x16x32_bf16(p0[mi], qn0[ni], a1[mi][ni], 0, 0, 0);
                a2[mi][ni] = __builtin_amdgcn_mfma_f32_16x16x32_bf16(p0[mi], qn1[ni], a2[mi][ni], 0, 0, 0);
                a3[mi][ni] = __builtin_amdgcn_mfma_f32_16x16x32_bf16(p1[mi], qn0[ni], a3[mi][ni], 0, 0, 0);
                a4[mi][ni] = __builtin_amdgcn_mfma_f32_16x16x32_bf16(p1[mi], qn1[ni], a4[mi][ni], 0, 0, 0);
            }
    }
    float* Gp = Gpart + (size_t)(blockIdx.x * 14 + b) * 5 * 4096;
#define STORE_Z(zidx, ACC)                                                     \
    for (int mi = 0; mi < 2; ++mi)                                             \
        for (int r = 0; r < 4; ++r)                                            \
            for (int ni = 0; ni < 2; ++ni)                                     \
                Gp[zidx * 4096 + (mo + mi * 16 + q * 4 + r) * 64 + no + ni * 16 + lm] = ACC[mi][ni][r];
    STORE_Z(0, a0) STORE_Z(1, a1) STORE_Z(2, a2) STORE_Z(3, a3) STORE_Z(4, a4)
#undef STORE_Z
}

__global__ __launch_bounds__(256) void gram_reduce(
    const float* __restrict__ Gpart, float* __restrict__ G)
{
    const int e = blockIdx.x * 256 + threadIdx.x;
    float s = 0.f;
#pragma unroll
    for (int ks = 0; ks < 32; ++ks) s += Gpart[(size_t)ks * 286720 + e];
    G[e] = s;
}

// ---------------------------------------------------------------------------
// Sandwich (unchanged).  grid (14, 9), block 256
// ---------------------------------------------------------------------------
__global__ __launch_bounds__(256) void sandwich(
    const float* __restrict__ thc_w, const float* __restrict__ phc_w,
    const float* __restrict__ thc_b, const float* __restrict__ phc_b,
    const float* __restrict__ thh_w, const float* __restrict__ phh_w,
    const float* __restrict__ thh_b, const float* __restrict__ phh_b,
    const float* __restrict__ thw_w, const float* __restrict__ phw_w,
    const float* __restrict__ thw_b, const float* __restrict__ phw_b,
    const float* __restrict__ G, const float* __restrict__ S,
    float* __restrict__ f1, float* __restrict__ f2)
{
    __shared__ float Wt[64][65], Wp[64][65], Gl[64][65], Tl[64][65];
    __shared__ float sth[64], sph[64], uu[64], vv[64], btl[64], bpl[64];
    const int b = blockIdx.x, y = blockIdx.y, tid = threadIdx.x;
    const float *Wth_g, *Wph_g, *bth_g, *bph_g, *Gp;
    float* outp; int dl = 0, dp = 0; float Kn;
    if (y == 0) {
        Wth_g = thc_w; Wph_g = phc_w; bth_g = thc_b; bph_g = phc_b;
        Gp = G + (size_t)(b * 5) * 4096; Kn = 16384.f;
        outp = f1 + (size_t)b * 4096;
    } else {
        const int part = (y - 1) / 4, e = (y - 1) & 3;
        dl = e >> 1; dp = e & 1;
        if (part == 0) { Wth_g = thh_w; Wph_g = phh_w; bth_g = thh_b; bph_g = phh_b; }
        else           { Wth_g = thw_w; Wph_g = phw_w; bth_g = thw_b; bph_g = phw_b; }
        Gp = G + (size_t)(b * 5 + 1 + e) * 4096; Kn = 8192.f;
        outp = f2 + (size_t)(part * 14 + b) * 16384;
    }
#pragma unroll
    for (int i = 0; i < 4; ++i) {
        const int id = tid + 256 * i;
        const int r = id >> 4, c4 = (id & 15) * 4;
        float4 v = *(const float4*)&Wth_g[r * 64 + c4];
        Wt[r][c4] = v.x; Wt[r][c4 + 1] = v.y; Wt[r][c4 + 2] = v.z; Wt[r][c4 + 3] = v.w;
        float4 u = *(const float4*)&Wph_g[r * 64 + c4];
        Wp[r][c4] = u.x; Wp[r][c4 + 1] = u.y; Wp[r][c4 + 2] = u.z; Wp[r][c4 + 3] = u.w;
        float4 g = *(const float4*)&Gp[r * 64 + c4];
        Gl[r][c4] = g.x; Gl[r][c4 + 1] = g.y; Gl[r][c4 + 2] = g.z; Gl[r][c4 + 3] = g.w;
    }
    if (tid < 64) {
        if (y == 0) { const float sf = S[b * 128 + tid] + S[b * 128 + 64 + tid]; sth[tid] = sf; sph[tid] = sf; }
        else { sth[tid] = S[dl * 64 + tid]; sph[tid] = S[b * 128 + dp * 64 + tid]; }
        btl[tid] = bth_g[tid]; bpl[tid] = bph_g[tid];
    }
    __syncthreads();
    if (tid < 64) {
        float su = 0.f, sv = 0.f;
        for (int c = 0; c < 64; ++c) { su += Wt[tid][c] * sth[c]; sv += Wp[tid][c] * sph[c]; }
        uu[tid] = su; vv[tid] = sv;
    }
    const int t = tid & 63, qq = tid >> 6;
    float r16[16];
#pragma unroll
    for (int i = 0; i < 16; ++i) r16[i] = 0.f;
    for (int c = 0; c < 64; ++c) {
        const float fv = Wt[t][c];
#pragma unroll
        for (int i = 0; i < 16; ++i) r16[i] += fv * Gl[c][qq * 16 + i];
    }
#pragma unroll
    for (int i = 0; i < 16; ++i) Tl[t][qq * 16 + i] = r16[i];
    __syncthreads();
#pragma unroll
    for (int i = 0; i < 16; ++i) r16[i] = 0.f;
    for (int c = 0; c < 64; ++c) {
        const float tv = Tl[t][c];
#pragma unroll
        for (int i = 0; i < 16; ++i) r16[i] += tv * Wp[qq * 16 + i][c];
    }
    if (y == 0) {
#pragma unroll
        for (int i = 0; i < 16; ++i) {
            const int d = qq * 16 + i;
            outp[t * 64 + d] = r16[i] + uu[t] * bpl[d] + btl[t] * vv[d] + Kn * btl[t] * bpl[d];
        }
    } else {
#pragma unroll
        for (int i = 0; i < 16; ++i) {
            const int tp = qq * 16 + i;
            outp[(2 * t + dl) * 128 + 2 * tp + dp] =
                r16[i] + uu[t] * bpl[tp] + btl[t] * vv[tp] + Kn * btl[t] * bpl[tp];
        }
    }
}

// ---------------------------------------------------------------------------
// Merged softmax + bias dots + de-interleave (unchanged)
// ---------------------------------------------------------------------------
__global__ __launch_bounds__(256) void softmax_all(
    const float* __restrict__ f1, const float* __restrict__ f2,
    const float* __restrict__ gcb, const float* __restrict__ ghb,
    const float* __restrict__ gwb,
    unsigned short* __restrict__ o1, unsigned short* __restrict__ o2d,
    float* __restrict__ B1, float* __restrict__ B2)
{
    __shared__ float red[256];
    __shared__ float mxA[128], invA[128];
    __shared__ float bgl[64];
    const int bx = blockIdx.x, tid = threadIdx.x;
    if (bx < 14) {
        const float* Fb = f1 + (size_t)bx * 4096;
        unsigned short* Ob = o1 + (size_t)bx * 4096;
        if (tid < 64) bgl[tid] = gcb[tid];
        const int d = tid & 63, qq = tid >> 6;
        float mx = -1e30f;
        for (int c = qq * 16; c < qq * 16 + 16; ++c) mx = fmaxf(mx, Fb[c * 64 + d]);
        red[tid] = mx;
        __syncthreads();
        if (tid < 64) mxA[tid] = fmaxf(fmaxf(red[tid], red[64 + tid]), fmaxf(red[128 + tid], red[192 + tid]));
        __syncthreads();
        const float m = mxA[d];
        float s = 0.f;
        for (int c = qq * 16; c < qq * 16 + 16; ++c) s += __expf(Fb[c * 64 + d] - m);
        red[tid] = s;
        __syncthreads();
        if (tid < 64) invA[tid] = 1.f / (red[tid] + red[64 + tid] + red[128 + tid] + red[192 + tid]);
        __syncthreads();
        const int e0 = tid * 16;
        const int d0 = e0 & 63;
        float bp = 0.f;
#pragma unroll
        for (int i = 0; i < 16; i += 4) {
            us4 r4;
            float v0 = __expf(Fb[e0 + i] - mxA[d0 + i]) * invA[d0 + i];
            float v1 = __expf(Fb[e0 + i + 1] - mxA[d0 + i + 1]) * invA[d0 + i + 1];
            float v2 = __expf(Fb[e0 + i + 2] - mxA[d0 + i + 2]) * invA[d0 + i + 2];
            float v3 = __expf(Fb[e0 + i + 3] - mxA[d0 + i + 3]) * invA[d0 + i + 3];
            bp += v0 * bgl[d0 + i] + v1 * bgl[d0 + i + 1] + v2 * bgl[d0 + i + 2] + v3 * bgl[d0 + i + 3];
            r4.x = f2bf(v0); r4.y = f2bf(v1); r4.z = f2bf(v2); r4.w = f2bf(v3);
            *(us4*)&Ob[e0 + i] = r4;
        }
        red[tid] = bp;
        __syncthreads();
        if (tid < 64)
            B1[bx * 64 + tid] = red[tid * 4] + red[tid * 4 + 1] + red[tid * 4 + 2] + red[tid * 4 + 3];
    } else {
        const int idx = bx - 14;
        const float* Fb = f2 + (size_t)idx * 16384;
        if (tid < 64) bgl[tid] = (idx < 14) ? ghb[tid] : gwb[tid];
        const int j = tid & 127, ih = tid >> 7;
        float mx = -1e30f;
        for (int i = ih * 64; i < ih * 64 + 64; ++i) mx = fmaxf(mx, Fb[i * 128 + j]);
        red[tid] = mx;
        __syncthreads();
        if (tid < 128) mxA[tid] = fmaxf(red[tid], red[128 + tid]);
        __syncthreads();
        const float m = mxA[j];
        float s = 0.f;
        for (int i = ih * 64; i < ih * 64 + 64; ++i) s += __expf(Fb[i * 128 + j] - m);
        red[tid] = s;
        __syncthreads();
        if (tid < 128) invA[tid] = 1.f / (red[tid] + red[128 + tid]);
        __syncthreads();
        const int e0 = tid * 64;
        const int irow = tid >> 1;
        const int j0 = e0 & 127;
        unsigned short vt[2][32];
        float bp = 0.f;
        for (int ii = 0; ii < 64; ++ii) {
            const int jj = j0 + ii;
            const float v = __expf(Fb[e0 + ii] - mxA[jj]) * invA[jj];
            bp += v * bgl[jj >> 1];
            vt[jj & 1][ii >> 1] = f2bf(v);
        }
        unsigned short* Od = o2d + (size_t)idx * 16384 + irow * 64 + (j0 >> 1);
#pragma unroll
        for (int dlt = 0; dlt < 2; ++dlt)
#pragma unroll
            for (int ss = 0; ss < 32; ss += 4)
                *(us4*)&Od[dlt * 8192 + ss] = *(us4*)&vt[dlt][ss];
        red[tid] = bp;
        __syncthreads();
        if (tid < 128) B2[idx * 128 + tid] = red[2 * tid] + red[2 * tid + 1];
    }
}

// ---------------------------------------------------------------------------
// kmat via MFMA (unchanged).  grid (14, 3), block 256
// ---------------------------------------------------------------------------
__global__ __launch_bounds__(256) void kmat(
    const unsigned short* __restrict__ f16_1, const unsigned short* __restrict__ f2d,
    const unsigned short* __restrict__ gT16,
    unsigned short* __restrict__ K1, unsigned short* __restrict__ K2)
{
    const int b = blockIdx.x, y = blockIdx.y, tid = threadIdx.x;
    const int w = tid >> 6, l = tid & 63, lm = l & 15, q = l >> 4;
    if (y == 0) {
        const unsigned short* A = f16_1 + (size_t)b * 4096;
        const unsigned short* Bm = gT16;
        const int mo = (w & 1) * 32, no = (w >> 1) * 32;
        f32x4 acc[2][2] = {};
#pragma unroll
        for (int ks = 0; ks < 2; ++ks) {
            const int k = ks * 32 + q * 8;
            bf16x8 a[2], bb[2];
#pragma unroll
            for (int mi = 0; mi < 2; ++mi) a[mi] = *(const bf16x8*)&A[(mo + mi * 16 + lm) * 64 + k];
#pragma unroll
            for (int ni = 0; ni < 2; ++ni) bb[ni] = *(const bf16x8*)&Bm[(no + ni * 16 + lm) * 64 + k];
#pragma unroll
            for (int mi = 0; mi < 2; ++mi)
#pragma unroll
                for (int ni = 0; ni < 2; ++ni)
                    acc[mi][ni] = __builtin_amdgcn_mfma_f32_16x16x32_bf16(a[mi], bb[ni], acc[mi][ni], 0, 0, 0);
        }
        unsigned short* Kp = K1 + (size_t)b * 4096;
#pragma unroll
        for (int mi = 0; mi < 2; ++mi)
#pragma unroll
            for (int r = 0; r < 4; ++r)
#pragma unroll
                for (int ni = 0; ni < 2; ++ni)
                    Kp[(mo + mi * 16 + q * 4 + r) * 64 + no + ni * 16 + lm] = f2bf(acc[mi][ni][r]);
    } else {
        const int part = y - 1;
        const unsigned short* Bm = gT16 + (size_t)(1 + part) * 4096;
        unsigned short* Kp = K2 + (size_t)(part * 14 + b) * 16384;
        for (int dlt = 0; dlt < 2; ++dlt) {
            const unsigned short* A = f2d + (size_t)(part * 14 + b) * 16384 + dlt * 8192;
            const int mo = (w & 1) * 64, no = (w >> 1) * 32;
            f32x4 acc[4][2] = {};
#pragma unroll
            for (int ks = 0; ks < 2; ++ks) {
                const int k = ks * 32 + q * 8;
                bf16x8 a[4], bb[2];
#pragma unroll
                for (int mi = 0; mi < 4; ++mi) a[mi] = *(const bf16x8*)&A[(mo + mi * 16 + lm) * 64 + k];
#pragma unroll
                for (int ni = 0; ni < 2; ++ni) bb[ni] = *(const bf16x8*)&Bm[(no + ni * 16 + lm) * 64 + k];
#pragma unroll
                for (int mi = 0; mi < 4; ++mi)
#pragma unroll
                    for (int ni = 0; ni < 2; ++ni)
                        acc[mi][ni] = __builtin_amdgcn_mfma_f32_16x16x32_bf16(a[mi], bb[ni], acc[mi][ni], 0, 0, 0);
            }
#pragma unroll
            for (int mi = 0; mi < 4; ++mi)
#pragma unroll
                for (int r = 0; r < 4; ++r)
#pragma unroll
                    for (int ni = 0; ni < 2; ++ni)
                        Kp[dlt * 8192 + (mo + mi * 16 + q * 4 + r) * 64 + no + ni * 16 + lm] = f2bf(acc[mi][ni][r]);
        }
    }
}

// ---------------------------------------------------------------------------
// Fused PV + fold + residual.  Block computes out tile [64 o][64 pix] for
// b in {by, by+7} (2 batches).  grid (256, 7) = 1792 blocks (~7/CU).
// ---------------------------------------------------------------------------
__device__ __forceinline__ void s1_p1(
    const unsigned short* __restrict__ XT, const unsigned short* __restrict__ K1,
    const float* __restrict__ B1, int b, int h1,
    int mo, int no, int lm, int q, unsigned short (*Yb)[LP])
{
    f32x4 acc[2][2] = {};
    const unsigned short* Xb = XT + (size_t)b * CN;
    const unsigned short* Kb = K1 + (size_t)b * 4096;
#pragma unroll
    for (int ks = 0; ks < 2; ++ks) {
        const int c0 = ks * 32 + q * 8;
        bf16x8 a[2], bb[2];
#pragma unroll
        for (int mi = 0; mi < 2; ++mi)
            a[mi] = *(const bf16x8*)&Xb[((size_t)(mo + mi * 16 + lm) * 256 + h1) * 64 + c0];
#pragma unroll
        for (int ni = 0; ni < 2; ++ni)
            bb[ni] = *(const bf16x8*)&Kb[(no + ni * 16 + lm) * 64 + c0];
#pragma unroll
        for (int mi = 0; mi < 2; ++mi)
#pragma unroll
            for (int ni = 0; ni < 2; ++ni)
                acc[mi][ni] = __builtin_amdgcn_mfma_f32_16x16x32_bf16(a[mi], bb[ni], acc[mi][ni], 0, 0, 0);
    }
#pragma unroll
    for (int mi = 0; mi < 2; ++mi)
#pragma unroll
        for (int r = 0; r < 4; ++r) {
            const int c2 = mo + mi * 16 + q * 4 + r;
#pragma unroll
            for (int ni = 0; ni < 2; ++ni) {
                const int c = no + ni * 16 + lm;
                Yb[c][c2] = f2bf(acc[mi][ni][r] + B1[b * 64 + c]);
            }
        }
}

__device__ __forceinline__ void s1_p23(
    const unsigned short* __restrict__ XT, const unsigned short* __restrict__ K2,
    const float* __restrict__ B2, int part, int b, int h2, int i0,
    int mo, int no, int lm, int q, unsigned short (*Yb)[LP])
{
    f32x4 acc[2][2] = {};
    const unsigned short* Xb = XT + (size_t)b * CN;
    const unsigned short* Kb = K2 + (size_t)(part * 14 + b) * 16384;
    const float* Bb = B2 + (part * 14 + b) * 128;
#pragma unroll
    for (int dlt = 0; dlt < 2; ++dlt)
#pragma unroll
        for (int ks = 0; ks < 2; ++ks) {
            const int c0 = ks * 32 + q * 8;
            bf16x8 a[2], bb[2];
#pragma unroll
            for (int mi = 0; mi < 2; ++mi)
                a[mi] = *(const bf16x8*)&Xb[((size_t)dlt * 8192 + (size_t)(mo + mi * 16 + lm) * 128 + h2) * 64 + c0];
#pragma unroll
            for (int ni = 0; ni < 2; ++ni)
                bb[ni] = *(const bf16x8*)&Kb[dlt * 8192 + (i0 + no + ni * 16 + lm) * 64 + c0];
#pragma unroll
            for (int mi = 0; mi < 2; ++mi)
#pragma unroll
                for (int ni = 0; ni < 2; ++ni)
                    acc[mi][ni] = __builtin_amdgcn_mfma_f32_16x16x32_bf16(a[mi], bb[ni], acc[mi][ni], 0, 0, 0);
        }
#pragma unroll
    for (int mi = 0; mi < 2; ++mi)
#pragma unroll
        for (int r = 0; r < 4; ++r) {
            const int c2 = mo + mi * 16 + q * 4 + r;
#pragma unroll
            for (int ni = 0; ni < 2; ++ni) {
                const int iiL = no + ni * 16 + lm;
                Yb[iiL][c2] = f2bf(acc[mi][ni][r] + Bb[i0 + iiL]);
            }
        }
}

__device__ __forceinline__ void s2(
    const unsigned short* __restrict__ M16, int z, int b,
    int mo, int no, int lm, int q, const unsigned short (*Yb)[LP],
    f32x4 (*oacc)[2])
{
    const unsigned short* Mp = M16 + (size_t)(z * 14 + b) * 4096;
#pragma unroll
    for (int ks = 0; ks < 2; ++ks) {
        const int c0 = ks * 32 + q * 8;
        bf16x8 a[2], bb[2];
#pragma unroll
        for (int mi = 0; mi < 2; ++mi)
            a[mi] = *(const bf16x8*)&Mp[(mo + mi * 16 + lm) * 64 + c0];
#pragma unroll
        for (int ni = 0; ni < 2; ++ni)
            bb[ni] = *(const bf16x8*)&Yb[no + ni * 16 + lm][c0];
#pragma unroll
        for (int mi = 0; mi < 2; ++mi)
#pragma unroll
            for (int ni = 0; ni < 2; ++ni)
                oacc[mi][ni] = __builtin_amdgcn_mfma_f32_16x16x32_bf16(a[mi], bb[ni], oacc[mi][ni], 0, 0, 0);
    }
}

__global__ __launch_bounds__(256) void pvfold(
    const unsigned short* __restrict__ XT,
    const unsigned short* __restrict__ K1, const float* __restrict__ B1,
    const unsigned short* __restrict__ K2, const float* __restrict__ B2,
    const unsigned short* __restrict__ M16,
    const unsigned short* __restrict__ Wcomb,
    float* __restrict__ Out)
{
    __shared__ unsigned short Ys[2][64][LP];
    const int tid = threadIdx.x;
    const int w = tid >> 6, l = tid & 63, lm = l & 15, q = l >> 4;
    const int P0 = blockIdx.x * 64;
    const int h1 = blockIdx.x;
    const int h2 = blockIdx.x >> 1;
    const int i0 = (blockIdx.x & 1) * 64;
    const int by = blockIdx.y;      // handles b = by and by + 7
    const int mo = (w & 1) * 32, no = (w >> 1) * 32;
    f32x4 oacc[2][2] = {};

    // residual: out += Wcomb[:, b*64:] @ xT[b][P0..P0+64][:]  (2 batches)
#pragma unroll
    for (int bi = 0; bi < 2; ++bi) {
        const int b = by + bi * 7;
#pragma unroll
        for (int ks = 0; ks < 2; ++ks) {
            const int c0 = ks * 32 + q * 8;
            bf16x8 a[2], bb[2];
#pragma unroll
            for (int mi = 0; mi < 2; ++mi)
                a[mi] = *(const bf16x8*)&Wcomb[(mo + mi * 16 + lm) * 896 + b * 64 + c0];
#pragma unroll
            for (int ni = 0; ni < 2; ++ni)
                bb[ni] = *(const bf16x8*)&XT[(size_t)b * CN + (size_t)(P0 + no + ni * 16 + lm) * 64 + c0];
#pragma unroll
            for (int mi = 0; mi < 2; ++mi)
#pragma unroll
                for (int ni = 0; ni < 2; ++ni)
                    oacc[mi][ni] = __builtin_amdgcn_mfma_f32_16x16x32_bf16(a[mi], bb[ni], oacc[mi][ni], 0, 0, 0);
        }
    }

    // pipelined PV: per b: p1 -> z0, p2 -> z1, p3 -> z2 (double-buffered)
    int cur = 0;
    s1_p1(XT, K1, B1, by, h1, mo, no, lm, q, Ys[0]);
#pragma unroll
    for (int bi = 0; bi < 2; ++bi) {
        const int b = by + bi * 7;
        __syncthreads();
        s2(M16, 0, b, mo, no, lm, q, (const unsigned short (*)[LP])Ys[cur], oacc);
        s1_p23(XT, K2, B2, 0, b, h2, i0, mo, no, lm, q, Ys[cur ^ 1]);
        __syncthreads();
        s2(M16, 1, b, mo, no, lm, q, (const unsigned short (*)[LP])Ys[cur ^ 1], oacc);
        s1_p23(XT, K2, B2, 1, b, h2, i0, mo, no, lm, q, Ys[cur]);
        __syncthreads();
        s2(M16, 2, b, mo, no, lm, q, (const unsigned short (*)[LP])Ys[cur], oacc);
        if (bi == 0) s1_p1(XT, K1, B1, by + 7, h1, mo, no, lm, q, Ys[cur ^ 1]);
        cur ^= 1;
    }

#pragma unroll
    for (int mi = 0; mi < 2; ++mi)
#pragma unroll
        for (int r = 0; r < 4; ++r) {
            const int o = mo + mi * 16 + q * 4 + r;
#pragma unroll
            for (int ni = 0; ni < 2; ++ni)
                atomicAdd(&Out[(size_t)o * NPIX + P0 + no + ni * 16 + lm], oacc[mi][ni][r]);
        }
}

// out = leaky(out + cb[o])
__global__ __launch_bounds__(256) void leaky_cb(float* __restrict__ O, const float* __restrict__ cb)
{
    const int i = blockIdx.x * 256 + threadIdx.x;
    float4 v = ((float4*)O)[i];
    const float b = cb[(i * 4) >> 14];
    v.x += b; v.y += b; v.z += b; v.w += b;
    v.x = v.x >= 0.f ? v.x : 0.2f * v.x;
    v.y = v.y >= 0.f ? v.y : 0.2f * v.y;
    v.z = v.z >= 0.f ? v.z : 0.2f * v.z;
    v.w = v.w >= 0.f ? v.w : 0.2f * v.w;
    ((float4*)O)[i] = v;
}

extern "C" void kernel_launch(void* const* d_in, const int* in_sizes, int n_in,
                              void* d_out, int out_size, void* d_ws, size_t ws_size,
                              hipStream_t stream)
{
    const float* x     = (const float*)d_in[0];
    const float* gc_w  = (const float*)d_in[1];
    const float* gc_b  = (const float*)d_in[2];
    const float* thc_w = (const float*)d_in[3];
    const float* thc_b = (const float*)d_in[4];
    const float* phc_w = (const float*)d_in[5];
    const float* phc_b = (const float*)d_in[6];
    const float* Wc_w  = (const float*)d_in[7];
    const float* Wc_b  = (const float*)d_in[8];
    const float* gh_w  = (const float*)d_in[9];
    const float* gh_b  = (const float*)d_in[10];
    const float* thh_w = (const float*)d_in[11];
    const float* thh_b = (const float*)d_in[12];
    const float* phh_w = (const float*)d_in[13];
    const float* phh_b = (const float*)d_in[14];
    const float* Wh_w  = (const float*)d_in[15];
    const float* Wh_b  = (const float*)d_in[16];
    const float* gw_w  = (const float*)d_in[17];
    const float* gw_b  = (const float*)d_in[18];
    const float* thw_w = (const float*)d_in[19];
    const float* thw_b = (const float*)d_in[20];
    const float* phw_w = (const float*)d_in[21];
    const float* phw_b = (const float*)d_in[22];
    const float* Ww_w  = (const float*)d_in[23];
    const float* Ww_b  = (const float*)d_in[24];
    const float* fus_w = (const float*)d_in[25];
    const float* fus_b = (const float*)d_in[26];

    float* out = (float*)d_out;

    char* p = (char*)d_ws;
    unsigned short* xb   = (unsigned short*)p; p += (size_t)BURST * CN * 2;
    unsigned short* xT   = (unsigned short*)p; p += (size_t)BURST * CN * 2;
    float*          Gpart = (float*)p;         p += (size_t)32 * 286720 * 4;
    float*          Gbuf = (float*)p;          p += (size_t)BURST * 5 * 4096 * 4;
    float*          sbuf = (float*)p;          p += (size_t)BURST * 2 * 64 * 4;
    float*          f1b  = (float*)p;          p += (size_t)BURST * 4096 * 4;
    float*          f2b  = (float*)p;          p += (size_t)2 * BURST * 16384 * 4;
    unsigned short* f16_1 = (unsigned short*)p; p += (size_t)BURST * 4096 * 2;
    unsigned short* f2d  = (unsigned short*)p; p += (size_t)2 * BURST * 16384 * 2;
    unsigned short* K1   = (unsigned short*)p; p += (size_t)BURST * 4096 * 2;
    unsigned short* K2   = (unsigned short*)p; p += (size_t)2 * BURST * 16384 * 2;
    float*          B1   = (float*)p;          p += (size_t)BURST * 64 * 4;
    float*          B2   = (float*)p;          p += (size_t)2 * BURST * 128 * 4;
    unsigned short* M16  = (unsigned short*)p; p += (size_t)42 * 4096 * 2;
    unsigned short* Wc16 = (unsigned short*)p; p += (size_t)64 * 896 * 2;
    unsigned short* gT16 = (unsigned short*)p; p += (size_t)3 * 4096 * 2;
    float*          cbv  = (float*)p;          p += 256;

    hipMemsetAsync(sbuf, 0, (size_t)BURST * 2 * 64 * 4, stream);
    hipMemsetAsync(out, 0, (size_t)NF * NPIX * 4, stream);

    cast_x<<<dim3(128, 14), 256, 0, stream>>>(x, xb, xT, sbuf);
    precompute<<<109, 256, 0, stream>>>(fus_w, fus_b, Wc_w, Wc_b, Wh_w, Wh_b, Ww_w, Ww_b,
                                        gc_w, gh_w, gw_w, M16, Wc16, cbv, gT16);
    gram<<<dim3(32, 14), 256, 0, stream>>>(xb, Gpart);
    gram_reduce<<<1120, 256, 0, stream>>>(Gpart, Gbuf);
    sandwich<<<dim3(14, 9), 256, 0, stream>>>(
        thc_w, phc_w, thc_b, phc_b, thh_w, phh_w, thh_b, phh_b,
        thw_w, phw_w, thw_b, phw_b, Gbuf, sbuf, f1b, f2b);
    softmax_all<<<42, 256, 0, stream>>>(f1b, f2b, gc_b, gh_b, gw_b,
                                        f16_1, f2d, B1, B2);
    kmat<<<dim3(14, 3), 256, 0, stream>>>(f16_1, f2d, gT16, K1, K2);
    pvfold<<<dim3(256, 7), 256, 0, stream>>>(xT, K1, B1, K2, B2, M16, Wc16, out);
    leaky_cb<<<1024, 256, 0, stream>>>(out, cbv);
}

// Round 9
// 331.400 us; speedup vs baseline: 1.0294x; 1.0121x over previous
//
#include <hip/hip_runtime.h>

#define NF 64
#define BURST 14
#define NPIX 16384
#define CN (NF * NPIX)
#define LP 72

typedef short bf16x8 __attribute__((ext_vector_type(8)));
typedef float f32x4 __attribute__((ext_vector_type(4)));
typedef unsigned short us4 __attribute__((ext_vector_type(4)));

__device__ inline unsigned short f2bf(float f) {
    unsigned int u = __float_as_uint(f);
    return (unsigned short)((u + 0x7fffu + ((u >> 16) & 1u)) >> 16);
}
__device__ inline float bf2f(unsigned short u) {
    return __uint_as_float(((unsigned int)u) << 16);
}

// ---------------------------------------------------------------------------
// x fp32 [b][c][pix] -> xb bf16 same layout + xT bf16 [b][pix][c] + half sums
// grid (128, 14), block 256
// ---------------------------------------------------------------------------
__global__ __launch_bounds__(256) void cast_x(const float* __restrict__ X,
                                              unsigned short* __restrict__ XB,
                                              unsigned short* __restrict__ XT,
                                              float* __restrict__ S)
{
    __shared__ unsigned short Xs[128][LP];
    __shared__ float red[256];
    const int tid = threadIdx.x;
    const int p0 = blockIdx.x * 128;
    const int b = blockIdx.y;
    const size_t boff = (size_t)b * CN;
#pragma unroll
    for (int i = 0; i < 8; ++i) {
        const int id = tid + 256 * i;
        const int c = id >> 5, p4 = (id & 31) * 4;
        float4 v = *(const float4*)&X[boff + (size_t)c * NPIX + p0 + p4];
        us4 r;
        r.x = f2bf(v.x); r.y = f2bf(v.y); r.z = f2bf(v.z); r.w = f2bf(v.w);
        *(us4*)&XB[boff + (size_t)c * NPIX + p0 + p4] = r;
        Xs[p4 + 0][c] = r.x; Xs[p4 + 1][c] = r.y;
        Xs[p4 + 2][c] = r.z; Xs[p4 + 3][c] = r.w;
    }
    __syncthreads();
#pragma unroll
    for (int i = 0; i < 4; ++i) {
        const int id = tid + 256 * i;
        const int row = id >> 3, c8 = (id & 7) * 8;
        *(bf16x8*)&XT[boff + (size_t)(p0 + row) * 64 + c8] = *(const bf16x8*)&Xs[row][c8];
    }
    {
        const int c = tid & 63, qq = tid >> 6;
        float sv = 0.f;
        for (int pp = qq * 32; pp < qq * 32 + 32; ++pp) sv += bf2f(Xs[pp][c]);
        red[tid] = sv;
        __syncthreads();
        if (tid < 64) {
            const float t = red[tid] + red[64 + tid] + red[128 + tid] + red[192 + tid];
            atomicAdd(&S[(b * 2 + (p0 >= 8192 ? 1 : 0)) * 64 + tid], t);
        }
    }
}

// ---------------------------------------------------------------------------
// Precompute (unchanged)
// ---------------------------------------------------------------------------
__global__ __launch_bounds__(256) void precompute(
    const float* __restrict__ fus_w, const float* __restrict__ fus_b,
    const float* __restrict__ Wc, const float* __restrict__ bWc,
    const float* __restrict__ Wh, const float* __restrict__ bWh,
    const float* __restrict__ Ww, const float* __restrict__ bWw,
    const float* __restrict__ gcw, const float* __restrict__ ghw,
    const float* __restrict__ gww,
    unsigned short* __restrict__ M16, unsigned short* __restrict__ Wc16,
    float* __restrict__ cb, unsigned short* __restrict__ gT16)
{
    const int blk = blockIdx.x, tid = threadIdx.x;
    if (blk < 42) {
        __shared__ float Fl[64][65];
        __shared__ float Wl[64][65];
        const int g = blk / 14, b = blk % 14;
        const float* Wg = (g == 0) ? Wc : (g == 1) ? Wh : Ww;
#pragma unroll
        for (int i = 0; i < 4; ++i) {
            const int id = tid + 256 * i;
            const int r = id >> 4, c4 = (id & 15) * 4;
            float4 v = *(const float4*)&fus_w[r * 2688 + g * 896 + b * 64 + c4];
            Fl[r][c4] = v.x; Fl[r][c4 + 1] = v.y; Fl[r][c4 + 2] = v.z; Fl[r][c4 + 3] = v.w;
            float4 u = *(const float4*)&Wg[r * 64 + c4];
            Wl[r][c4] = u.x; Wl[r][c4 + 1] = u.y; Wl[r][c4 + 2] = u.z; Wl[r][c4 + 3] = u.w;
        }
        __syncthreads();
        const int o = tid & 63, qq = tid >> 6;
        float s[16];
#pragma unroll
        for (int i = 0; i < 16; ++i) s[i] = 0.f;
        for (int c2 = 0; c2 < 64; ++c2) {
            const float fv = Fl[o][c2];
#pragma unroll
            for (int i = 0; i < 16; ++i) s[i] += fv * Wl[c2][qq * 16 + i];
        }
        unsigned short* Mout = M16 + (size_t)blk * 4096;
#pragma unroll
        for (int i = 0; i < 16; i += 4) {
            us4 r4; r4.x = f2bf(s[i]); r4.y = f2bf(s[i + 1]); r4.z = f2bf(s[i + 2]); r4.w = f2bf(s[i + 3]);
            *(us4*)&Mout[o * 64 + qq * 16 + i] = r4;
        }
    } else if (blk < 98) {
        const int e0 = (blk - 42) * 1024 + tid * 4;
        const int o = e0 / 896, bc = e0 - o * 896;
        float4 a = *(const float4*)&fus_w[o * 2688 + bc];
        float4 b2 = *(const float4*)&fus_w[o * 2688 + 896 + bc];
        float4 c3 = *(const float4*)&fus_w[o * 2688 + 1792 + bc];
        us4 r;
        r.x = f2bf(a.x + b2.x + c3.x); r.y = f2bf(a.y + b2.y + c3.y);
        r.z = f2bf(a.z + b2.z + c3.z); r.w = f2bf(a.w + b2.w + c3.w);
        *(us4*)&Wc16[e0] = r;
    } else if (blk < 106) {
        __shared__ float red[256];
        const int o = (blk - 98) * 8 + (tid >> 5);
        const int lane = tid & 31;
        float s = 0.f;
        for (int t = 0; t < 84; ++t) {
            const int ch = lane + 32 * t;
            const int g = ch / 896, c2 = ch & 63;
            const float bg = (g == 0) ? bWc[c2] : (g == 1) ? bWh[c2] : bWw[c2];
            s += fus_w[o * 2688 + ch] * bg;
        }
        red[tid] = s;
        __syncthreads();
        if (tid < 8) {
            const int oo = (blk - 98) * 8 + tid;
            float t = fus_b[oo];
            for (int i = 0; i < 32; ++i) t += red[tid * 32 + i];
            cb[oo] = t;
        }
    } else {
        const int g = blk - 106;
        const float* wg = (g == 0) ? gcw : (g == 1) ? ghw : gww;
        unsigned short* dst = gT16 + (size_t)g * 4096;
        for (int e = tid; e < 4096; e += 256) {
            const int cp = e >> 6, d = e & 63;
            dst[e] = f2bf(wg[d * 64 + cp]);
        }
    }
}

// ---------------------------------------------------------------------------
// Merged Gram (unchanged): grid (32, 14), block 256
// ---------------------------------------------------------------------------
__global__ __launch_bounds__(256) void gram(
    const unsigned short* __restrict__ XB, float* __restrict__ Gpart)
{
    const int tid = threadIdx.x;
    const int w = tid >> 6, l = tid & 63, lm = l & 15, q = l >> 4;
    const int b = blockIdx.y;
    const int mo = (w & 1) * 32, no = (w >> 1) * 32;
    const unsigned short* P = XB;
    const unsigned short* Q = XB + (size_t)b * CN;
    f32x4 a0[2][2] = {}, a1[2][2] = {}, a2[2][2] = {}, a3[2][2] = {}, a4[2][2] = {};
#pragma unroll 2
    for (int ki = 0; ki < 8; ++ki) {
        const int k = blockIdx.x * 256 + ki * 32 + q * 8;
        bf16x8 p0[2], p1[2], qm0[2], qm1[2], qn0[2], qn1[2];
#pragma unroll
        for (int mi = 0; mi < 2; ++mi) {
            const size_t rm = (size_t)(mo + mi * 16 + lm) * NPIX;
            const size_t rn = (size_t)(no + mi * 16 + lm) * NPIX;
            p0[mi]  = *(const bf16x8*)&P[rm + k];
            p1[mi]  = *(const bf16x8*)&P[rm + 8192 + k];
            qm0[mi] = *(const bf16x8*)&Q[rm + k];
            qm1[mi] = *(const bf16x8*)&Q[rm + 8192 + k];
            qn0[mi] = *(const bf16x8*)&Q[rn + k];
            qn1[mi] = *(const bf16x8*)&Q[rn + 8192 + k];
        }
#pragma unroll
        for (int mi = 0; mi < 2; ++mi)
#pragma unroll
            for (int ni = 0; ni < 2; ++ni) {
                a0[mi][ni] = __builtin_amdgcn_mfma_f32_16x16x32_bf16(qm0[mi], qn0[ni], a0[mi][ni], 0, 0, 0);
                a0[mi][ni] = __builtin_amdgcn_mfma_f32_16x16x32_bf16(qm1[mi], qn1[ni], a0[mi][ni], 0, 0, 0);
                a1[mi][ni] = __builtin_amdgcn_mfma_f32_16x16x32_bf16(p0[mi], qn0[ni], a1[mi][ni], 0, 0, 0);
                a2[mi][ni] = __builtin_amdgcn_mfma_f32_16x16x32_bf16(p0[mi], qn1[ni], a2[mi][ni], 0, 0, 0);
                a3[mi][ni] = __builtin_amdgcn_mfma_f32_16x16x32_bf16(p1[mi], qn0[ni], a3[mi][ni], 0, 0, 0);
                a4[mi][ni] = __builtin_amdgcn_mfma_f32_16x16x32_bf16(p1[mi], qn1[ni], a4[mi][ni], 0, 0, 0);
            }
    }
    float* Gp = Gpart + (size_t)(blockIdx.x * 14 + b) * 5 * 4096;
#define STORE_Z(zidx, ACC)                                                     \
    for (int mi = 0; mi < 2; ++mi)                                             \
        for (int r = 0; r < 4; ++r)                                            \
            for (int ni = 0; ni < 2; ++ni)                                     \
                Gp[zidx * 4096 + (mo + mi * 16 + q * 4 + r) * 64 + no + ni * 16 + lm] = ACC[mi][ni][r];
    STORE_Z(0, a0) STORE_Z(1, a1) STORE_Z(2, a2) STORE_Z(3, a3) STORE_Z(4, a4)
#undef STORE_Z
}

__global__ __launch_bounds__(256) void gram_reduce(
    const float* __restrict__ Gpart, float* __restrict__ G)
{
    const int e = blockIdx.x * 256 + threadIdx.x;
    float s = 0.f;
#pragma unroll
    for (int ks = 0; ks < 32; ++ks) s += Gpart[(size_t)ks * 286720 + e];
    G[e] = s;
}

// ---------------------------------------------------------------------------
// Sandwich (unchanged).  grid (14, 9), block 256
// ---------------------------------------------------------------------------
__global__ __launch_bounds__(256) void sandwich(
    const float* __restrict__ thc_w, const float* __restrict__ phc_w,
    const float* __restrict__ thc_b, const float* __restrict__ phc_b,
    const float* __restrict__ thh_w, const float* __restrict__ phh_w,
    const float* __restrict__ thh_b, const float* __restrict__ phh_b,
    const float* __restrict__ thw_w, const float* __restrict__ phw_w,
    const float* __restrict__ thw_b, const float* __restrict__ phw_b,
    const float* __restrict__ G, const float* __restrict__ S,
    float* __restrict__ f1, float* __restrict__ f2)
{
    __shared__ float Wt[64][65], Wp[64][65], Gl[64][65], Tl[64][65];
    __shared__ float sth[64], sph[64], uu[64], vv[64], btl[64], bpl[64];
    const int b = blockIdx.x, y = blockIdx.y, tid = threadIdx.x;
    const float *Wth_g, *Wph_g, *bth_g, *bph_g, *Gp;
    float* outp; int dl = 0, dp = 0; float Kn;
    if (y == 0) {
        Wth_g = thc_w; Wph_g = phc_w; bth_g = thc_b; bph_g = phc_b;
        Gp = G + (size_t)(b * 5) * 4096; Kn = 16384.f;
        outp = f1 + (size_t)b * 4096;
    } else {
        const int part = (y - 1) / 4, e = (y - 1) & 3;
        dl = e >> 1; dp = e & 1;
        if (part == 0) { Wth_g = thh_w; Wph_g = phh_w; bth_g = thh_b; bph_g = phh_b; }
        else           { Wth_g = thw_w; Wph_g = phw_w; bth_g = thw_b; bph_g = phw_b; }
        Gp = G + (size_t)(b * 5 + 1 + e) * 4096; Kn = 8192.f;
        outp = f2 + (size_t)(part * 14 + b) * 16384;
    }
#pragma unroll
    for (int i = 0; i < 4; ++i) {
        const int id = tid + 256 * i;
        const int r = id >> 4, c4 = (id & 15) * 4;
        float4 v = *(const float4*)&Wth_g[r * 64 + c4];
        Wt[r][c4] = v.x; Wt[r][c4 + 1] = v.y; Wt[r][c4 + 2] = v.z; Wt[r][c4 + 3] = v.w;
        float4 u = *(const float4*)&Wph_g[r * 64 + c4];
        Wp[r][c4] = u.x; Wp[r][c4 + 1] = u.y; Wp[r][c4 + 2] = u.z; Wp[r][c4 + 3] = u.w;
        float4 g = *(const float4*)&Gp[r * 64 + c4];
        Gl[r][c4] = g.x; Gl[r][c4 + 1] = g.y; Gl[r][c4 + 2] = g.z; Gl[r][c4 + 3] = g.w;
    }
    if (tid < 64) {
        if (y == 0) { const float sf = S[b * 128 + tid] + S[b * 128 + 64 + tid]; sth[tid] = sf; sph[tid] = sf; }
        else { sth[tid] = S[dl * 64 + tid]; sph[tid] = S[b * 128 + dp * 64 + tid]; }
        btl[tid] = bth_g[tid]; bpl[tid] = bph_g[tid];
    }
    __syncthreads();
    if (tid < 64) {
        float su = 0.f, sv = 0.f;
        for (int c = 0; c < 64; ++c) { su += Wt[tid][c] * sth[c]; sv += Wp[tid][c] * sph[c]; }
        uu[tid] = su; vv[tid] = sv;
    }
    const int t = tid & 63, qq = tid >> 6;
    float r16[16];
#pragma unroll
    for (int i = 0; i < 16; ++i) r16[i] = 0.f;
    for (int c = 0; c < 64; ++c) {
        const float fv = Wt[t][c];
#pragma unroll
        for (int i = 0; i < 16; ++i) r16[i] += fv * Gl[c][qq * 16 + i];
    }
#pragma unroll
    for (int i = 0; i < 16; ++i) Tl[t][qq * 16 + i] = r16[i];
    __syncthreads();
#pragma unroll
    for (int i = 0; i < 16; ++i) r16[i] = 0.f;
    for (int c = 0; c < 64; ++c) {
        const float tv = Tl[t][c];
#pragma unroll
        for (int i = 0; i < 16; ++i) r16[i] += tv * Wp[qq * 16 + i][c];
    }
    if (y == 0) {
#pragma unroll
        for (int i = 0; i < 16; ++i) {
            const int d = qq * 16 + i;
            outp[t * 64 + d] = r16[i] + uu[t] * bpl[d] + btl[t] * vv[d] + Kn * btl[t] * bpl[d];
        }
    } else {
#pragma unroll
        for (int i = 0; i < 16; ++i) {
            const int tp = qq * 16 + i;
            outp[(2 * t + dl) * 128 + 2 * tp + dp] =
                r16[i] + uu[t] * bpl[tp] + btl[t] * vv[tp] + Kn * btl[t] * bpl[tp];
        }
    }
}

// ---------------------------------------------------------------------------
// Merged softmax + bias dots + de-interleave (unchanged)
// ---------------------------------------------------------------------------
__global__ __launch_bounds__(256) void softmax_all(
    const float* __restrict__ f1, const float* __restrict__ f2,
    const float* __restrict__ gcb, const float* __restrict__ ghb,
    const float* __restrict__ gwb,
    unsigned short* __restrict__ o1, unsigned short* __restrict__ o2d,
    float* __restrict__ B1, float* __restrict__ B2)
{
    __shared__ float red[256];
    __shared__ float mxA[128], invA[128];
    __shared__ float bgl[64];
    const int bx = blockIdx.x, tid = threadIdx.x;
    if (bx < 14) {
        const float* Fb = f1 + (size_t)bx * 4096;
        unsigned short* Ob = o1 + (size_t)bx * 4096;
        if (tid < 64) bgl[tid] = gcb[tid];
        const int d = tid & 63, qq = tid >> 6;
        float mx = -1e30f;
        for (int c = qq * 16; c < qq * 16 + 16; ++c) mx = fmaxf(mx, Fb[c * 64 + d]);
        red[tid] = mx;
        __syncthreads();
        if (tid < 64) mxA[tid] = fmaxf(fmaxf(red[tid], red[64 + tid]), fmaxf(red[128 + tid], red[192 + tid]));
        __syncthreads();
        const float m = mxA[d];
        float s = 0.f;
        for (int c = qq * 16; c < qq * 16 + 16; ++c) s += __expf(Fb[c * 64 + d] - m);
        red[tid] = s;
        __syncthreads();
        if (tid < 64) invA[tid] = 1.f / (red[tid] + red[64 + tid] + red[128 + tid] + red[192 + tid]);
        __syncthreads();
        const int e0 = tid * 16;
        const int d0 = e0 & 63;
        float bp = 0.f;
#pragma unroll
        for (int i = 0; i < 16; i += 4) {
            us4 r4;
            float v0 = __expf(Fb[e0 + i] - mxA[d0 + i]) * invA[d0 + i];
            float v1 = __expf(Fb[e0 + i + 1] - mxA[d0 + i + 1]) * invA[d0 + i + 1];
            float v2 = __expf(Fb[e0 + i + 2] - mxA[d0 + i + 2]) * invA[d0 + i + 2];
            float v3 = __expf(Fb[e0 + i + 3] - mxA[d0 + i + 3]) * invA[d0 + i + 3];
            bp += v0 * bgl[d0 + i] + v1 * bgl[d0 + i + 1] + v2 * bgl[d0 + i + 2] + v3 * bgl[d0 + i + 3];
            r4.x = f2bf(v0); r4.y = f2bf(v1); r4.z = f2bf(v2); r4.w = f2bf(v3);
            *(us4*)&Ob[e0 + i] = r4;
        }
        red[tid] = bp;
        __syncthreads();
        if (tid < 64)
            B1[bx * 64 + tid] = red[tid * 4] + red[tid * 4 + 1] + red[tid * 4 + 2] + red[tid * 4 + 3];
    } else {
        const int idx = bx - 14;
        const float* Fb = f2 + (size_t)idx * 16384;
        if (tid < 64) bgl[tid] = (idx < 14) ? ghb[tid] : gwb[tid];
        const int j = tid & 127, ih = tid >> 7;
        float mx = -1e30f;
        for (int i = ih * 64; i < ih * 64 + 64; ++i) mx = fmaxf(mx, Fb[i * 128 + j]);
        red[tid] = mx;
        __syncthreads();
        if (tid < 128) mxA[tid] = fmaxf(red[tid], red[128 + tid]);
        __syncthreads();
        const float m = mxA[j];
        float s = 0.f;
        for (int i = ih * 64; i < ih * 64 + 64; ++i) s += __expf(Fb[i * 128 + j] - m);
        red[tid] = s;
        __syncthreads();
        if (tid < 128) invA[tid] = 1.f / (red[tid] + red[128 + tid]);
        __syncthreads();
        const int e0 = tid * 64;
        const int irow = tid >> 1;
        const int j0 = e0 & 127;
        unsigned short vt[2][32];
        float bp = 0.f;
        for (int ii = 0; ii < 64; ++ii) {
            const int jj = j0 + ii;
            const float v = __expf(Fb[e0 + ii] - mxA[jj]) * invA[jj];
            bp += v * bgl[jj >> 1];
            vt[jj & 1][ii >> 1] = f2bf(v);
        }
        unsigned short* Od = o2d + (size_t)idx * 16384 + irow * 64 + (j0 >> 1);
#pragma unroll
        for (int dlt = 0; dlt < 2; ++dlt)
#pragma unroll
            for (int ss = 0; ss < 32; ss += 4)
                *(us4*)&Od[dlt * 8192 + ss] = *(us4*)&vt[dlt][ss];
        red[tid] = bp;
        __syncthreads();
        if (tid < 128) B2[idx * 128 + tid] = red[2 * tid] + red[2 * tid + 1];
    }
}

// ---------------------------------------------------------------------------
// kmat via MFMA (unchanged).  grid (14, 3), block 256
// ---------------------------------------------------------------------------
__global__ __launch_bounds__(256) void kmat(
    const unsigned short* __restrict__ f16_1, const unsigned short* __restrict__ f2d,
    const unsigned short* __restrict__ gT16,
    unsigned short* __restrict__ K1, unsigned short* __restrict__ K2)
{
    const int b = blockIdx.x, y = blockIdx.y, tid = threadIdx.x;
    const int w = tid >> 6, l = tid & 63, lm = l & 15, q = l >> 4;
    if (y == 0) {
        const unsigned short* A = f16_1 + (size_t)b * 4096;
        const unsigned short* Bm = gT16;
        const int mo = (w & 1) * 32, no = (w >> 1) * 32;
        f32x4 acc[2][2] = {};
#pragma unroll
        for (int ks = 0; ks < 2; ++ks) {
            const int k = ks * 32 + q * 8;
            bf16x8 a[2], bb[2];
#pragma unroll
            for (int mi = 0; mi < 2; ++mi) a[mi] = *(const bf16x8*)&A[(mo + mi * 16 + lm) * 64 + k];
#pragma unroll
            for (int ni = 0; ni < 2; ++ni) bb[ni] = *(const bf16x8*)&Bm[(no + ni * 16 + lm) * 64 + k];
#pragma unroll
            for (int mi = 0; mi < 2; ++mi)
#pragma unroll
                for (int ni = 0; ni < 2; ++ni)
                    acc[mi][ni] = __builtin_amdgcn_mfma_f32_16x16x32_bf16(a[mi], bb[ni], acc[mi][ni], 0, 0, 0);
        }
        unsigned short* Kp = K1 + (size_t)b * 4096;
#pragma unroll
        for (int mi = 0; mi < 2; ++mi)
#pragma unroll
            for (int r = 0; r < 4; ++r)
#pragma unroll
                for (int ni = 0; ni < 2; ++ni)
                    Kp[(mo + mi * 16 + q * 4 + r) * 64 + no + ni * 16 + lm] = f2bf(acc[mi][ni][r]);
    } else {
        const int part = y - 1;
        const unsigned short* Bm = gT16 + (size_t)(1 + part) * 4096;
        unsigned short* Kp = K2 + (size_t)(part * 14 + b) * 16384;
        for (int dlt = 0; dlt < 2; ++dlt) {
            const unsigned short* A = f2d + (size_t)(part * 14 + b) * 16384 + dlt * 8192;
            const int mo = (w & 1) * 64, no = (w >> 1) * 32;
            f32x4 acc[4][2] = {};
#pragma unroll
            for (int ks = 0; ks < 2; ++ks) {
                const int k = ks * 32 + q * 8;
                bf16x8 a[4], bb[2];
#pragma unroll
                for (int mi = 0; mi < 4; ++mi) a[mi] = *(const bf16x8*)&A[(mo + mi * 16 + lm) * 64 + k];
#pragma unroll
                for (int ni = 0; ni < 2; ++ni) bb[ni] = *(const bf16x8*)&Bm[(no + ni * 16 + lm) * 64 + k];
#pragma unroll
                for (int mi = 0; mi < 4; ++mi)
#pragma unroll
                    for (int ni = 0; ni < 2; ++ni)
                        acc[mi][ni] = __builtin_amdgcn_mfma_f32_16x16x32_bf16(a[mi], bb[ni], acc[mi][ni], 0, 0, 0);
            }
#pragma unroll
            for (int mi = 0; mi < 4; ++mi)
#pragma unroll
                for (int r = 0; r < 4; ++r)
#pragma unroll
                    for (int ni = 0; ni < 2; ++ni)
                        Kp[dlt * 8192 + (mo + mi * 16 + q * 4 + r) * 64 + no + ni * 16 + lm] = f2bf(acc[mi][ni][r]);
        }
    }
}

// ---------------------------------------------------------------------------
// pv_all: merged pv1 + pv2/3 (round-5 verified bodies), all loads dense.
// grid (64, 42): y<14 -> pv1 b=y; y>=14 -> part=(y-14)/14, b=(y-14)%14,
//   kx = x>>1, i0 = (x&1)*64.
// ---------------------------------------------------------------------------
__global__ __launch_bounds__(256) void pv_all(
    const unsigned short* __restrict__ XT,
    const unsigned short* __restrict__ K1, const float* __restrict__ B1,
    const unsigned short* __restrict__ K2, const float* __restrict__ B2,
    unsigned short* __restrict__ Y1, unsigned short* __restrict__ Y2,
    unsigned short* __restrict__ Y3)
{
    const int tid = threadIdx.x;
    const int w = tid >> 6, l = tid & 63, lm = l & 15, q = l >> 4;
    const int y = blockIdx.y;
    if (y < 14) {
        const int b = y;
        const int p0 = blockIdx.x * 256 + w * 64;
        const unsigned short* Xb = XT + (size_t)b * CN;
        const unsigned short* Kb = K1 + (size_t)b * 4096;
        f32x4 acc[4][4] = {};
#pragma unroll
        for (int ks = 0; ks < 2; ++ks) {
            const int c0 = ks * 32 + q * 8;
            bf16x8 a[4], bb[4];
#pragma unroll
            for (int mi = 0; mi < 4; ++mi) a[mi] = *(const bf16x8*)&Xb[(size_t)(p0 + mi * 16 + lm) * 64 + c0];
#pragma unroll
            for (int ni = 0; ni < 4; ++ni) bb[ni] = *(const bf16x8*)&Kb[(ni * 16 + lm) * 64 + c0];
#pragma unroll
            for (int mi = 0; mi < 4; ++mi)
#pragma unroll
                for (int ni = 0; ni < 4; ++ni)
                    acc[mi][ni] = __builtin_amdgcn_mfma_f32_16x16x32_bf16(a[mi], bb[ni], acc[mi][ni], 0, 0, 0);
        }
        unsigned short* Yb = Y1 + (size_t)b * CN;
#pragma unroll
        for (int mi = 0; mi < 4; ++mi)
#pragma unroll
            for (int r = 0; r < 4; ++r) {
                const int p = p0 + mi * 16 + q * 4 + r;
#pragma unroll
                for (int ni = 0; ni < 4; ++ni) {
                    const int c = ni * 16 + lm;
                    Yb[(size_t)p * 64 + c] = f2bf(acc[mi][ni][r] + B1[b * 64 + c]);
                }
            }
    } else {
        const int idx = y - 14;
        const int part = idx / 14, b = idx % 14;
        const int k00 = (blockIdx.x >> 1) * 256 + w * 64;
        const int i0 = (blockIdx.x & 1) * 64;
        const unsigned short* Xb = XT + (size_t)b * CN;
        const unsigned short* Kb = K2 + (size_t)(part * 14 + b) * 16384;
        const float* Bb = B2 + (part * 14 + b) * 128;
        f32x4 acc[4][4] = {};
#pragma unroll
        for (int dlt = 0; dlt < 2; ++dlt) {
#pragma unroll
            for (int ks = 0; ks < 2; ++ks) {
                const int c0 = ks * 32 + q * 8;
                bf16x8 a[4], bb[4];
#pragma unroll
                for (int mi = 0; mi < 4; ++mi)
                    a[mi] = *(const bf16x8*)&Xb[(size_t)(dlt * 8192 + k00 + mi * 16 + lm) * 64 + c0];
#pragma unroll
                for (int ni = 0; ni < 4; ++ni)
                    bb[ni] = *(const bf16x8*)&Kb[dlt * 8192 + (i0 + ni * 16 + lm) * 64 + c0];
#pragma unroll
                for (int mi = 0; mi < 4; ++mi)
#pragma unroll
                    for (int ni = 0; ni < 4; ++ni)
                        acc[mi][ni] = __builtin_amdgcn_mfma_f32_16x16x32_bf16(a[mi], bb[ni], acc[mi][ni], 0, 0, 0);
            }
        }
        unsigned short* Yb = (part ? Y3 : Y2) + (size_t)b * CN;
#pragma unroll
        for (int mi = 0; mi < 4; ++mi)
#pragma unroll
            for (int r = 0; r < 4; ++r) {
                const int k = k00 + mi * 16 + q * 4 + r;
#pragma unroll
                for (int ni = 0; ni < 4; ++ni) {
                    const int ii = i0 + ni * 16 + lm;
                    Yb[(size_t)k * 128 + ii] = f2bf(acc[mi][ni][r] + Bb[ii]);
                }
            }
    }
}

// ---------------------------------------------------------------------------
// yfold4: Out[o][pix] += sum_t M[z][t] @ y_z[t]  (z=0..2, LDS-transposed stage)
//                       + Wcomb[:,t] @ xT[t]     (z=3, direct dense stage)
// grid (128, 2, 4), block 256
// ---------------------------------------------------------------------------
__global__ __launch_bounds__(256) void yfold4(
    const unsigned short* __restrict__ M16,
    const unsigned short* __restrict__ Wcomb,
    const unsigned short* __restrict__ Y1, const unsigned short* __restrict__ Y2,
    const unsigned short* __restrict__ Y3, const unsigned short* __restrict__ XT,
    float* __restrict__ Out)
{
    __shared__ unsigned short As[64][LP];
    __shared__ unsigned short Ss[128][LP];
    const int tid = threadIdx.x;
    const int z = blockIdx.z;
    const unsigned short* S = (z == 0) ? Y1 : (z == 1) ? Y2 : (z == 2) ? Y3 : XT;
    const int p0 = blockIdx.x * 128;
    const int t0 = blockIdx.y * 7;
    const int w = tid >> 6, l = tid & 63, lm = l & 15, q = l >> 4;
    const int mo = (w & 1) * 32;
    const int no = (w >> 1) * 64;
    f32x4 acc[2][4] = {};

    for (int t = t0; t < t0 + 7; ++t) {
        __syncthreads();
        if (z < 3) {
            const unsigned short* Ap = M16 + (size_t)(z * 14 + t) * 4096;
#pragma unroll
            for (int i = 0; i < 2; ++i) {
                const int ch = tid + 256 * i;
                const int row = ch >> 3, c8 = (ch & 7) * 8;
                *(bf16x8*)&As[row][c8] = *(const bf16x8*)&Ap[row * 64 + c8];
            }
#pragma unroll
            for (int i = 0; i < 4; ++i) {
                const int id = tid + 256 * i;
                const int c = id & 63, p8 = (id >> 6) * 8;
                bf16x8 v = *(const bf16x8*)&S[(size_t)t * CN + (size_t)c * NPIX + p0 + p8];
#pragma unroll
                for (int j = 0; j < 8; ++j) Ss[p8 + j][c] = (unsigned short)v[j];
            }
        } else {
#pragma unroll
            for (int i = 0; i < 2; ++i) {
                const int ch = tid + 256 * i;
                const int row = ch >> 3, c8 = (ch & 7) * 8;
                *(bf16x8*)&As[row][c8] = *(const bf16x8*)&Wcomb[row * 896 + t * 64 + c8];
            }
#pragma unroll
            for (int i = 0; i < 4; ++i) {
                const int id = tid + 256 * i;
                const int row = id >> 3, c8 = (id & 7) * 8;
                *(bf16x8*)&Ss[row][c8] = *(const bf16x8*)&S[(size_t)t * CN + (size_t)(p0 + row) * 64 + c8];
            }
        }
        __syncthreads();
#pragma unroll
        for (int ks = 0; ks < 2; ++ks) {
            const int c0 = ks * 32 + q * 8;
            bf16x8 a[2], bb[4];
#pragma unroll
            for (int mi = 0; mi < 2; ++mi) a[mi] = *(const bf16x8*)&As[mo + mi * 16 + lm][c0];
#pragma unroll
            for (int ni = 0; ni < 4; ++ni) bb[ni] = *(const bf16x8*)&Ss[no + ni * 16 + lm][c0];
#pragma unroll
            for (int mi = 0; mi < 2; ++mi)
#pragma unroll
                for (int ni = 0; ni < 4; ++ni)
                    acc[mi][ni] = __builtin_amdgcn_mfma_f32_16x16x32_bf16(a[mi], bb[ni], acc[mi][ni], 0, 0, 0);
        }
    }
#pragma unroll
    for (int mi = 0; mi < 2; ++mi)
#pragma unroll
        for (int r = 0; r < 4; ++r) {
            const int o = mo + mi * 16 + q * 4 + r;
#pragma unroll
            for (int ni = 0; ni < 4; ++ni)
                atomicAdd(&Out[(size_t)o * NPIX + p0 + no + ni * 16 + lm], acc[mi][ni][r]);
        }
}

// out = leaky(out + cb[o])
__global__ __launch_bounds__(256) void leaky_cb(float* __restrict__ O, const float* __restrict__ cb)
{
    const int i = blockIdx.x * 256 + threadIdx.x;
    float4 v = ((float4*)O)[i];
    const float b = cb[(i * 4) >> 14];
    v.x += b; v.y += b; v.z += b; v.w += b;
    v.x = v.x >= 0.f ? v.x : 0.2f * v.x;
    v.y = v.y >= 0.f ? v.y : 0.2f * v.y;
    v.z = v.z >= 0.f ? v.z : 0.2f * v.z;
    v.w = v.w >= 0.f ? v.w : 0.2f * v.w;
    ((float4*)O)[i] = v;
}

extern "C" void kernel_launch(void* const* d_in, const int* in_sizes, int n_in,
                              void* d_out, int out_size, void* d_ws, size_t ws_size,
                              hipStream_t stream)
{
    const float* x     = (const float*)d_in[0];
    const float* gc_w  = (const float*)d_in[1];
    const float* gc_b  = (const float*)d_in[2];
    const float* thc_w = (const float*)d_in[3];
    const float* thc_b = (const float*)d_in[4];
    const float* phc_w = (const float*)d_in[5];
    const float* phc_b = (const float*)d_in[6];
    const float* Wc_w  = (const float*)d_in[7];
    const float* Wc_b  = (const float*)d_in[8];
    const float* gh_w  = (const float*)d_in[9];
    const float* gh_b  = (const float*)d_in[10];
    const float* thh_w = (const float*)d_in[11];
    const float* thh_b = (const float*)d_in[12];
    const float* phh_w = (const float*)d_in[13];
    const float* phh_b = (const float*)d_in[14];
    const float* Wh_w  = (const float*)d_in[15];
    const float* Wh_b  = (const float*)d_in[16];
    const float* gw_w  = (const float*)d_in[17];
    const float* gw_b  = (const float*)d_in[18];
    const float* thw_w = (const float*)d_in[19];
    const float* thw_b = (const float*)d_in[20];
    const float* phw_w = (const float*)d_in[21];
    const float* phw_b = (const float*)d_in[22];
    const float* Ww_w  = (const float*)d_in[23];
    const float* Ww_b  = (const float*)d_in[24];
    const float* fus_w = (const float*)d_in[25];
    const float* fus_b = (const float*)d_in[26];

    float* out = (float*)d_out;

    char* p = (char*)d_ws;
    unsigned short* xb   = (unsigned short*)p; p += (size_t)BURST * CN * 2;
    unsigned short* xT   = (unsigned short*)p; p += (size_t)BURST * CN * 2;
    unsigned short* y1   = (unsigned short*)p; p += (size_t)BURST * CN * 2;
    unsigned short* y2   = (unsigned short*)p; p += (size_t)BURST * CN * 2;
    unsigned short* y3   = (unsigned short*)p; p += (size_t)BURST * CN * 2;
    float*          Gbuf = (float*)p;          p += (size_t)BURST * 5 * 4096 * 4;
    float*          sbuf = (float*)p;          p += (size_t)BURST * 2 * 64 * 4;
    float*          f1b  = (float*)p;          p += (size_t)BURST * 4096 * 4;
    float*          f2b  = (float*)p;          p += (size_t)2 * BURST * 16384 * 4;
    unsigned short* f16_1 = (unsigned short*)p; p += (size_t)BURST * 4096 * 2;
    unsigned short* f2d  = (unsigned short*)p; p += (size_t)2 * BURST * 16384 * 2;
    unsigned short* K1   = (unsigned short*)p; p += (size_t)BURST * 4096 * 2;
    unsigned short* K2   = (unsigned short*)p; p += (size_t)2 * BURST * 16384 * 2;
    float*          B1   = (float*)p;          p += (size_t)BURST * 64 * 4;
    float*          B2   = (float*)p;          p += (size_t)2 * BURST * 128 * 4;
    unsigned short* M16  = (unsigned short*)p; p += (size_t)42 * 4096 * 2;
    unsigned short* Wc16 = (unsigned short*)p; p += (size_t)64 * 896 * 2;
    unsigned short* gT16 = (unsigned short*)p; p += (size_t)3 * 4096 * 2;
    float*          cbv  = (float*)p;          p += 256;

    // Gram partials alias y1/y2 (dead before pv_all writes them):
    float* Gpart = (float*)y1;   // 32*286720*4 = 36.7 MB < y1+y2 (58.7 MB)

    hipMemsetAsync(sbuf, 0, (size_t)BURST * 2 * 64 * 4, stream);
    hipMemsetAsync(out, 0, (size_t)NF * NPIX * 4, stream);

    cast_x<<<dim3(128, 14), 256, 0, stream>>>(x, xb, xT, sbuf);
    precompute<<<109, 256, 0, stream>>>(fus_w, fus_b, Wc_w, Wc_b, Wh_w, Wh_b, Ww_w, Ww_b,
                                        gc_w, gh_w, gw_w, M16, Wc16, cbv, gT16);
    gram<<<dim3(32, 14), 256, 0, stream>>>(xb, Gpart);
    gram_reduce<<<1120, 256, 0, stream>>>(Gpart, Gbuf);
    sandwich<<<dim3(14, 9), 256, 0, stream>>>(
        thc_w, phc_w, thc_b, phc_b, thh_w, phh_w, thh_b, phh_b,
        thw_w, phw_w, thw_b, phw_b, Gbuf, sbuf, f1b, f2b);
    softmax_all<<<42, 256, 0, stream>>>(f1b, f2b, gc_b, gh_b, gw_b,
                                        f16_1, f2d, B1, B2);
    kmat<<<dim3(14, 3), 256, 0, stream>>>(f16_1, f2d, gT16, K1, K2);
    pv_all<<<dim3(64, 42), 256, 0, stream>>>(xT, K1, B1, K2, B2, y1, y2, y3);
    yfold4<<<dim3(128, 2, 4), 256, 0, stream>>>(M16, Wc16, y1, y2, y3, xT, out);
    leaky_cb<<<1024, 256, 0, stream>>>(out, cbv);
}